// Round 1
// baseline (461.529 us; speedup 1.0000x reference)
//
#include <hip/hip_runtime.h>
#include <math.h>

static constexpr int B  = 8;
static constexpr int T  = 800;
static constexpr int L  = 192000;
static constexpr int NB = 24;
static constexpr float SCALE = (float)(800.0 / 192000.0);  // T/L

__device__ __forceinline__ float sigf(float x) { return 1.0f / (1.0f + expf(-x)); }
__device__ __forceinline__ float leaky(float x) { return x >= 0.0f ? x : 0.1f * x; }

__device__ __forceinline__ void interp_idx(int l, int& i0, int& i1, float& w) {
    float pos = ((float)l + 0.5f) * SCALE - 0.5f;
    pos = fminf(fmaxf(pos, 0.0f), (float)(T - 1));
    i0 = (int)floorf(pos);
    i1 = min(i0 + 1, T - 1);
    w = pos - (float)i0;
}

// ---------- noise predictor conv1: 128 -> 256, k=3, pad=1, leaky ----------
__global__ __launch_bounds__(256) void k_np1(const float* __restrict__ cond,
                                             const float* __restrict__ w1,
                                             const float* __restrict__ b1,
                                             float* __restrict__ h1) {
    __shared__ float xs[128 * 18];
    const int b = blockIdx.y;
    const int t0 = blockIdx.x * 16;
    const int tid = threadIdx.x;
    for (int i = tid; i < 128 * 18; i += 256) {
        int cin = i / 18, j = i % 18;
        int t = t0 + j - 1;
        xs[i] = (t >= 0 && t < T) ? cond[(b * 128 + cin) * T + t] : 0.0f;
    }
    __syncthreads();
    const int cout = tid;
    float acc[16];
#pragma unroll
    for (int t = 0; t < 16; ++t) acc[t] = 0.0f;
    for (int cin = 0; cin < 128; ++cin) {
        const float* wp = w1 + (cout * 128 + cin) * 3;
        float w0 = wp[0], wA = wp[1], wB = wp[2];
        const float* xp = xs + cin * 18;
        float xv[18];
#pragma unroll
        for (int j = 0; j < 18; ++j) xv[j] = xp[j];
#pragma unroll
        for (int t = 0; t < 16; ++t)
            acc[t] += w0 * xv[t] + wA * xv[t + 1] + wB * xv[t + 2];
    }
    const float bias = b1[cout];
#pragma unroll
    for (int t = 0; t < 16; ++t)
        h1[(b * 256 + cout) * T + t0 + t] = leaky(acc[t] + bias);
}

// ---------- noise predictor conv2: 256 -> 256, k=3, pad=1, leaky ----------
__global__ __launch_bounds__(256) void k_np2(const float* __restrict__ h1,
                                             const float* __restrict__ w2,
                                             const float* __restrict__ b2,
                                             float* __restrict__ h2) {
    __shared__ float xs[256 * 18];
    const int b = blockIdx.y;
    const int t0 = blockIdx.x * 16;
    const int tid = threadIdx.x;
    for (int i = tid; i < 256 * 18; i += 256) {
        int cin = i / 18, j = i % 18;
        int t = t0 + j - 1;
        xs[i] = (t >= 0 && t < T) ? h1[(b * 256 + cin) * T + t] : 0.0f;
    }
    __syncthreads();
    const int cout = tid;
    float acc[16];
#pragma unroll
    for (int t = 0; t < 16; ++t) acc[t] = 0.0f;
    for (int cin = 0; cin < 256; ++cin) {
        const float* wp = w2 + (cout * 256 + cin) * 3;
        float w0 = wp[0], wA = wp[1], wB = wp[2];
        const float* xp = xs + cin * 18;
        float xv[18];
#pragma unroll
        for (int j = 0; j < 18; ++j) xv[j] = xp[j];
#pragma unroll
        for (int t = 0; t < 16; ++t)
            acc[t] += w0 * xv[t] + wA * xv[t + 1] + wB * xv[t + 2];
    }
    const float bias = b2[cout];
#pragma unroll
    for (int t = 0; t < 16; ++t)
        h2[(b * 256 + cout) * T + t0 + t] = leaky(acc[t] + bias);
}

// ---------- noise predictor head: 256 -> 27 (1x1) + sigmoids ----------
__global__ __launch_bounds__(256) void k_np3(const float* __restrict__ h2,
                                             const float* __restrict__ w3,
                                             const float* __restrict__ b3,
                                             float* __restrict__ band,
                                             float* __restrict__ attack,
                                             float* __restrict__ inten) {
    const int b = blockIdx.y;
    const int t = blockIdx.x * 256 + threadIdx.x;
    if (t >= T) return;
    float acc[27];
#pragma unroll
    for (int c = 0; c < 27; ++c) acc[c] = b3[c];
    for (int cin = 0; cin < 256; ++cin) {
        float v = h2[(b * 256 + cin) * T + t];
#pragma unroll
        for (int c = 0; c < 27; ++c) acc[c] += v * w3[c * 256 + cin];
    }
#pragma unroll
    for (int c = 0; c < NB; ++c) band[(b * NB + c) * T + t] = sigf(acc[c]);
    attack[b * T + t] = sigf(acc[24]) * 10.0f;
    inten[b * T + t] = sigf(acc[26]);
}

// ---------- spectral shaper conv1: 128 -> 128, k=3, pad=1, leaky ----------
__global__ __launch_bounds__(128) void k_ss1(const float* __restrict__ cond,
                                             const float* __restrict__ w1,
                                             const float* __restrict__ b1,
                                             float* __restrict__ g) {
    __shared__ float xs[128 * 18];
    const int b = blockIdx.y;
    const int t0 = blockIdx.x * 16;
    const int tid = threadIdx.x;
    for (int i = tid; i < 128 * 18; i += 128) {
        int cin = i / 18, j = i % 18;
        int t = t0 + j - 1;
        xs[i] = (t >= 0 && t < T) ? cond[(b * 128 + cin) * T + t] : 0.0f;
    }
    __syncthreads();
    const int cout = tid;
    float acc[16];
#pragma unroll
    for (int t = 0; t < 16; ++t) acc[t] = 0.0f;
    for (int cin = 0; cin < 128; ++cin) {
        const float* wp = w1 + (cout * 128 + cin) * 3;
        float w0 = wp[0], wA = wp[1], wB = wp[2];
        const float* xp = xs + cin * 18;
        float xv[18];
#pragma unroll
        for (int j = 0; j < 18; ++j) xv[j] = xp[j];
#pragma unroll
        for (int t = 0; t < 16; ++t)
            acc[t] += w0 * xv[t] + wA * xv[t + 1] + wB * xv[t + 2];
    }
    const float bias = b1[cout];
#pragma unroll
    for (int t = 0; t < 16; ++t)
        g[(b * 128 + cout) * T + t0 + t] = leaky(acc[t] + bias);
}

// ---------- spectral shaper head: 128 -> 4 (1x1) + softmax over 4 ----------
__global__ __launch_bounds__(256) void k_ss2(const float* __restrict__ g,
                                             const float* __restrict__ w2,
                                             const float* __restrict__ b2,
                                             float* __restrict__ ntw) {
    const int b = blockIdx.y;
    const int t = blockIdx.x * 256 + threadIdx.x;
    if (t >= T) return;
    float acc[4] = {b2[0], b2[1], b2[2], b2[3]};
    for (int cin = 0; cin < 128; ++cin) {
        float v = g[(b * 128 + cin) * T + t];
#pragma unroll
        for (int c = 0; c < 4; ++c) acc[c] += v * w2[c * 128 + cin];
    }
    float m = fmaxf(fmaxf(acc[0], acc[1]), fmaxf(acc[2], acc[3]));
    float e0 = expf(acc[0] - m), e1 = expf(acc[1] - m);
    float e2 = expf(acc[2] - m), e3 = expf(acc[3] - m);
    float s = e0 + e1 + e2 + e3;
    ntw[(b * 4 + 0) * T + t] = e0 / s;
    ntw[(b * 4 + 1) * T + t] = e1 / s;
    ntw[(b * 4 + 2) * T + t] = e2 / s;
    ntw[(b * 4 + 3) * T + t] = e3 / s;
}

// ---------- noise-type FIR (4 x K=63, pad=31) + mix by upsampled ntw ----------
__global__ __launch_bounds__(256) void k_filter(const float* __restrict__ wn,
                                                const float* __restrict__ ntw,
                                                const float* __restrict__ ntf,
                                                float* __restrict__ filt) {
    __shared__ float xs[256 + 62];
    const int b = blockIdx.y;
    const int l0 = blockIdx.x * 256;
    const int tid = threadIdx.x;
    for (int i = tid; i < 318; i += 256) {
        int gl = l0 - 31 + i;
        xs[i] = (gl >= 0 && gl < L) ? wn[b * L + gl] : 0.0f;
    }
    __syncthreads();
    const int l = l0 + tid;
    int i0, i1; float w;
    interp_idx(l, i0, i1, w);
    float nu[4];
#pragma unroll
    for (int c = 0; c < 4; ++c) {
        float v0 = ntw[(b * 4 + c) * T + i0];
        float v1 = ntw[(b * 4 + c) * T + i1];
        nu[c] = v0 * (1.0f - w) + v1 * w;
    }
    float xv[63];
#pragma unroll
    for (int k = 0; k < 63; ++k) xv[k] = xs[tid + k];
    float f0 = 0.f, f1 = 0.f, f2 = 0.f, f3 = 0.f;
#pragma unroll
    for (int k = 0; k < 63; ++k) {
        float x = xv[k];
        f0 += x * ntf[0 * 63 + k];
        f1 += x * ntf[1 * 63 + k];
        f2 += x * ntf[2 * 63 + k];
        f3 += x * ntf[3 * 63 + k];
    }
    filt[b * L + l] = f0 * nu[0] + f1 * nu[1] + f2 * nu[2] + f3 * nu[3];
}

// ---------- 24-band filterbank (K=31, pad=15) + band mix + gate + outputs ----------
__device__ __forceinline__ float interp_arr(const float* __restrict__ a, int b, int p) {
    int i0, i1; float w;
    interp_idx(p, i0, i1, w);
    return a[b * T + i0] * (1.0f - w) + a[b * T + i1] * w;
}

__device__ __forceinline__ float gate_pre(const float* __restrict__ inten,
                                          const float* __restrict__ att, int b, int p) {
    float ip = interp_arr(inten, b, p);
    float diff = (p == 0) ? 0.0f : ip - interp_arr(inten, b, p - 1);
    float ar = interp_arr(att, b, p);
    float mask = diff > 0.1f ? 1.0f : 0.0f;
    float enh = fminf(fmaxf(ip + mask * ar * 0.3f, 0.0f), 1.0f);
    return diff > 0.0f ? enh : ip;
}

__device__ __forceinline__ int refl(int p) {
    return p < 0 ? -p : (p >= L ? 2 * L - 2 - p : p);
}

__global__ __launch_bounds__(256) void k_out(const float* __restrict__ filt,
                                             const float* __restrict__ band,
                                             const float* __restrict__ attack,
                                             const float* __restrict__ inten,
                                             const float* __restrict__ fbw,
                                             float* __restrict__ out) {
    __shared__ float xs[256 + 30];
    const int b = blockIdx.y;
    const int l0 = blockIdx.x * 256;
    const int tid = threadIdx.x;
    for (int i = tid; i < 286; i += 256) {
        int gl = l0 - 15 + i;
        xs[i] = (gl >= 0 && gl < L) ? filt[b * L + gl] : 0.0f;
    }
    __syncthreads();
    const int l = l0 + tid;

    float xv[31];
#pragma unroll
    for (int k = 0; k < 31; ++k) xv[k] = xs[tid + k];

    float bacc[NB];
#pragma unroll
    for (int c = 0; c < NB; ++c) bacc[c] = 0.0f;
#pragma unroll
    for (int k = 0; k < 31; ++k) {
        float x = xv[k];
#pragma unroll
        for (int c = 0; c < NB; ++c) bacc[c] += x * fbw[c * 31 + k];
    }

    int i0, i1; float w;
    interp_idx(l, i0, i1, w);
    float shaped = 0.0f;
#pragma unroll
    for (int c = 0; c < NB; ++c) {
        float v0 = band[(b * NB + c) * T + i0];
        float v1 = band[(b * NB + c) * T + i1];
        shaped += bacc[c] * (v0 * (1.0f - w) + v1 * w);
    }

    float gsum = 0.0f;
#pragma unroll
    for (int dp = -2; dp <= 2; ++dp)
        gsum += gate_pre(inten, attack, b, refl(l + dp));
    float gate = gsum * 0.2f;

    out[b * L + l] = shaped * gate;
    out[B * L + b * L + l] = gate;
}

extern "C" void kernel_launch(void* const* d_in, const int* in_sizes, int n_in,
                              void* d_out, int out_size, void* d_ws, size_t ws_size,
                              hipStream_t stream) {
    const float* cond  = (const float*)d_in[0];
    const float* wn    = (const float*)d_in[1];
    const float* np_w1 = (const float*)d_in[2];
    const float* np_b1 = (const float*)d_in[3];
    const float* np_w2 = (const float*)d_in[4];
    const float* np_b2 = (const float*)d_in[5];
    const float* np_w3 = (const float*)d_in[6];
    const float* np_b3 = (const float*)d_in[7];
    const float* ss_w1 = (const float*)d_in[8];
    const float* ss_b1 = (const float*)d_in[9];
    const float* ss_w2 = (const float*)d_in[10];
    const float* ss_b2 = (const float*)d_in[11];
    const float* fb_w  = (const float*)d_in[12];
    const float* nt_w  = (const float*)d_in[13];

    float* ws = (float*)d_ws;
    float* h1     = ws;                       // 8*256*800 = 1,638,400
    float* h2     = h1 + 8 * 256 * 800;       // 1,638,400
    float* band   = h2 + 8 * 256 * 800;       // 8*24*800 = 153,600
    float* attack = band + 8 * NB * 800;      // 6,400
    float* inten  = attack + 8 * 800;         // 6,400
    float* g      = inten + 8 * 800;          // 8*128*800 = 819,200
    float* ntw    = g + 8 * 128 * 800;        // 8*4*800 = 25,600
    float* filt   = ntw + 8 * 4 * 800;        // 8*192000 = 1,536,000
    float* out    = (float*)d_out;

    k_np1<<<dim3(50, 8), 256, 0, stream>>>(cond, np_w1, np_b1, h1);
    k_np2<<<dim3(50, 8), 256, 0, stream>>>(h1, np_w2, np_b2, h2);
    k_np3<<<dim3(4, 8), 256, 0, stream>>>(h2, np_w3, np_b3, band, attack, inten);
    k_ss1<<<dim3(50, 8), 128, 0, stream>>>(cond, ss_w1, ss_b1, g);
    k_ss2<<<dim3(4, 8), 256, 0, stream>>>(g, ss_w2, ss_b2, ntw);
    k_filter<<<dim3(750, 8), 256, 0, stream>>>(wn, ntw, nt_w, filt);
    k_out<<<dim3(750, 8), 256, 0, stream>>>(filt, band, attack, inten, fb_w, out);
}

// Round 2
// 339.235 us; speedup vs baseline: 1.3605x; 1.3605x over previous
//
#include <hip/hip_runtime.h>
#include <math.h>

static constexpr int B  = 8;
static constexpr int T  = 800;
static constexpr int L  = 192000;
static constexpr int NB = 24;
static constexpr float SCALE = 800.0f / 192000.0f;  // T/L

__device__ __forceinline__ float sigf(float x) { return 1.0f / (1.0f + __expf(-x)); }
__device__ __forceinline__ float leaky(float x) { return x >= 0.0f ? x : 0.1f * x; }

__device__ __forceinline__ void interp_idx(int l, int& i0, int& i1, float& w) {
    float pos = ((float)l + 0.5f) * SCALE - 0.5f;
    pos = fminf(fmaxf(pos, 0.0f), (float)(T - 1));
    i0 = (int)pos;                 // pos >= 0, trunc == floor
    i1 = min(i0 + 1, T - 1);
    w = pos - (float)i0;
}

// ---------------- weight transpose: [cout][cin][3] -> [cin][3][cout] ----------------
__global__ __launch_bounds__(256) void k_tw(const float* __restrict__ w1,
                                            const float* __restrict__ w2,
                                            const float* __restrict__ wss,
                                            float* __restrict__ wT1,
                                            float* __restrict__ wT2,
                                            float* __restrict__ wTs) {
    int idx = blockIdx.x * 256 + threadIdx.x;
    if (idx < 98304) {                       // np_w1 [256][128][3]
        int cout = idx / 384, r = idx % 384, cin = r / 3, k = r % 3;
        wT1[(cin * 3 + k) * 256 + cout] = w1[idx];
    } else if (idx < 98304 + 196608) {       // np_w2 [256][256][3]
        int j = idx - 98304;
        int cout = j / 768, r = j % 768, cin = r / 3, k = r % 3;
        wT2[(cin * 3 + k) * 256 + cout] = w2[j];
    } else if (idx < 344064) {               // ss_w1 [128][128][3]
        int j = idx - 294912;
        int cout = j / 384, r = j % 384, cin = r / 3, k = r % 3;
        wTs[(cin * 3 + k) * 128 + cout] = wss[j];
    }
}

// ---------------- k=3 conv, pad=1, leaky; thread = cout, tile = 16 t ----------------
template<int CIN, int COUT>
__global__ __launch_bounds__(COUT) void k_conv3(const float* __restrict__ x,
                                                const float* __restrict__ wT,
                                                const float* __restrict__ bias,
                                                float* __restrict__ y) {
    __shared__ float xs[CIN * 20];           // row stride 20 floats (80B, 16B-aligned)
    const int b = blockIdx.y;
    const int t0 = blockIdx.x * 16;
    const int tid = threadIdx.x;
    for (int i = tid; i < CIN * 18; i += COUT) {
        int cin = i / 18, col = i % 18;
        int t = t0 + col - 1;
        xs[cin * 20 + col] = (t >= 0 && t < T) ? x[(b * CIN + cin) * T + t] : 0.0f;
    }
    __syncthreads();
    float acc[16];
#pragma unroll
    for (int t = 0; t < 16; ++t) acc[t] = 0.0f;
    for (int cin = 0; cin < CIN; ++cin) {
        float w0 = wT[(cin * 3 + 0) * COUT + tid];
        float w1 = wT[(cin * 3 + 1) * COUT + tid];
        float w2 = wT[(cin * 3 + 2) * COUT + tid];
        const float4* xp4 = reinterpret_cast<const float4*>(xs + cin * 20);
        float4 q0 = xp4[0], q1 = xp4[1], q2 = xp4[2], q3 = xp4[3];
        float2 q4 = reinterpret_cast<const float2*>(xs + cin * 20)[8];
        float xv[18] = {q0.x,q0.y,q0.z,q0.w, q1.x,q1.y,q1.z,q1.w,
                        q2.x,q2.y,q2.z,q2.w, q3.x,q3.y,q3.z,q3.w, q4.x,q4.y};
#pragma unroll
        for (int t = 0; t < 16; ++t)
            acc[t] += w0 * xv[t] + w1 * xv[t + 1] + w2 * xv[t + 2];
    }
    float bv = bias[tid];
#pragma unroll
    for (int t = 0; t < 16; ++t)
        y[(b * COUT + tid) * T + t0 + t] = leaky(acc[t] + bv);
}

// ---------------- noise predictor head: 256 -> 27 (1x1) + sigmoids ----------------
__global__ __launch_bounds__(256) void k_np3(const float* __restrict__ h2,
                                             const float* __restrict__ w3,
                                             const float* __restrict__ b3,
                                             float* __restrict__ band,
                                             float* __restrict__ attack,
                                             float* __restrict__ inten) {
    __shared__ float ps[32][8][27];
    const int b = blockIdx.y;
    const int t0 = blockIdx.x * 32;
    const int tid = threadIdx.x;
    const int tl = tid >> 3, ch = tid & 7;
    const int t = t0 + tl;
    float acc[27];
#pragma unroll
    for (int c = 0; c < 27; ++c) acc[c] = 0.0f;
    for (int ci = 0; ci < 32; ++ci) {
        int cin = ch * 32 + ci;
        float v = h2[(b * 256 + cin) * T + t];
#pragma unroll
        for (int c = 0; c < 27; ++c) acc[c] += v * w3[c * 256 + cin];
    }
#pragma unroll
    for (int c = 0; c < 27; ++c) ps[tl][ch][c] = acc[c];
    __syncthreads();
    for (int i = tid; i < 32 * 27; i += 256) {
        int tt = i / 27, c = i % 27;
        float s = b3[c];
#pragma unroll
        for (int j = 0; j < 8; ++j) s += ps[tt][j][c];
        int gt = t0 + tt;
        if (c < NB) band[(b * NB + c) * T + gt] = sigf(s);
        else if (c == 24) attack[b * T + gt] = sigf(s) * 10.0f;
        else if (c == 26) inten[b * T + gt] = sigf(s);
    }
}

// ---------------- spectral shaper head: 128 -> 4 (1x1) + softmax ----------------
__global__ __launch_bounds__(256) void k_ss2(const float* __restrict__ g,
                                             const float* __restrict__ w2,
                                             const float* __restrict__ b2,
                                             float* __restrict__ ntw) {
    __shared__ float ps[32][8][4];
    __shared__ float rs[32][4];
    const int b = blockIdx.y;
    const int t0 = blockIdx.x * 32;
    const int tid = threadIdx.x;
    const int tl = tid >> 3, ch = tid & 7;
    const int t = t0 + tl;
    float acc[4] = {0.f, 0.f, 0.f, 0.f};
    for (int ci = 0; ci < 16; ++ci) {
        int cin = ch * 16 + ci;
        float v = g[(b * 128 + cin) * T + t];
#pragma unroll
        for (int c = 0; c < 4; ++c) acc[c] += v * w2[c * 128 + cin];
    }
#pragma unroll
    for (int c = 0; c < 4; ++c) ps[tl][ch][c] = acc[c];
    __syncthreads();
    if (tid < 128) {
        int tt = tid >> 2, c = tid & 3;
        float s = b2[c];
#pragma unroll
        for (int j = 0; j < 8; ++j) s += ps[tt][j][c];
        rs[tt][c] = s;
    }
    __syncthreads();
    if (tid < 32) {
        float a0 = rs[tid][0], a1 = rs[tid][1], a2 = rs[tid][2], a3 = rs[tid][3];
        float m = fmaxf(fmaxf(a0, a1), fmaxf(a2, a3));
        float e0 = __expf(a0 - m), e1 = __expf(a1 - m), e2 = __expf(a2 - m), e3 = __expf(a3 - m);
        float inv = 1.0f / (e0 + e1 + e2 + e3);
        int gt = t0 + tid;
        ntw[(b * 4 + 0) * T + gt] = e0 * inv;
        ntw[(b * 4 + 1) * T + gt] = e1 * inv;
        ntw[(b * 4 + 2) * T + gt] = e2 * inv;
        ntw[(b * 4 + 3) * T + gt] = e3 * inv;
    }
}

// ---------------- per-frame effective noise-type filter: g_all[b][f][63] ----------------
__global__ __launch_bounds__(256) void k_gfilt(const float* __restrict__ ntw,
                                               const float* __restrict__ ntf,
                                               float* __restrict__ g_all) {
    int idx = blockIdx.x * 256 + threadIdx.x;
    if (idx >= B * T * 63) return;
    int b = idx / (T * 63);
    int r = idx % (T * 63);
    int f = r / 63, k = r % 63;
    float s = 0.0f;
#pragma unroll
    for (int c = 0; c < 4; ++c)
        s += ntf[c * 63 + k] * ntw[(b * 4 + c) * T + f];
    g_all[idx] = s;
}

// ---------------- per-frame effective band filter: h_all[b][f][31] ----------------
__global__ __launch_bounds__(256) void k_hfilt(const float* __restrict__ band,
                                               const float* __restrict__ fbw,
                                               float* __restrict__ h_all) {
    int idx = blockIdx.x * 256 + threadIdx.x;
    if (idx >= B * T * 31) return;
    int b = idx / (T * 31);
    int r = idx % (T * 31);
    int f = r / 31, k = r % 31;
    float s = 0.0f;
#pragma unroll
    for (int c = 0; c < NB; ++c)
        s += fbw[c * 31 + k] * band[(b * NB + c) * T + f];
    h_all[idx] = s;
}

// ---------------- noise-type FIR + mix, via frame-lerped filters ----------------
__global__ __launch_bounds__(256) void k_filter(const float* __restrict__ wn,
                                                const float* __restrict__ g_all,
                                                float* __restrict__ filt) {
    __shared__ float xs[318];
    __shared__ float gl[4][63];
    const int b = blockIdx.y;
    const int l0 = blockIdx.x * 256;
    const int tid = threadIdx.x;
    for (int i = tid; i < 318; i += 256) {
        int gp = l0 - 31 + i;
        xs[i] = (gp >= 0 && gp < L) ? wn[b * L + gp] : 0.0f;
    }
    int f0, f1u; float wu;
    interp_idx(l0, f0, f1u, wu);
    if (tid < 252) {
        int j = tid / 63, k = tid % 63;
        int f = min(f0 + j, T - 1);
        gl[j][k] = g_all[(b * T + f) * 63 + k];
    }
    __syncthreads();
    const int l = l0 + tid;
    int i0, i1; float w;
    interp_idx(l, i0, i1, w);
    int d0 = min(max(i0 - f0, 0), 3);
    int d1 = min(max(i1 - f0, 0), 3);
    float a0 = 0.0f, a1 = 0.0f;
#pragma unroll
    for (int k = 0; k < 63; ++k) {
        float xk = xs[tid + k];
        a0 += xk * gl[d0][k];
        a1 += xk * gl[d1][k];
    }
    filt[b * L + l] = (1.0f - w) * a0 + w * a1;
}

// ---------------- filterbank mix + gate + outputs ----------------
__device__ __forceinline__ float interp_T(const float* __restrict__ a, int b, int p) {
    int i0, i1; float w;
    interp_idx(p, i0, i1, w);
    return a[b * T + i0] * (1.0f - w) + a[b * T + i1] * w;
}

__device__ __forceinline__ int refl(int p) {
    return p < 0 ? -p : (p >= L ? 2 * L - 2 - p : p);
}

__global__ __launch_bounds__(256) void k_out(const float* __restrict__ filt,
                                             const float* __restrict__ h_all,
                                             const float* __restrict__ attack,
                                             const float* __restrict__ inten,
                                             float* __restrict__ out) {
    __shared__ float xs[286];
    __shared__ float hl[4][31];
    __shared__ float ipl[261];   // ipl[i] = intensity_up(l0-3+i)
    __shared__ float gp[260];    // gp[i] = gate_pre(l0-2+i)  (reflected)
    const int b = blockIdx.y;
    const int l0 = blockIdx.x * 256;
    const int tid = threadIdx.x;
    for (int i = tid; i < 286; i += 256) {
        int p = l0 - 15 + i;
        xs[i] = (p >= 0 && p < L) ? filt[b * L + p] : 0.0f;
    }
    int f0, f1u; float wu;
    interp_idx(l0, f0, f1u, wu);
    if (tid < 124) {
        int j = tid / 31, k = tid % 31;
        int f = min(f0 + j, T - 1);
        hl[j][k] = h_all[(b * T + f) * 31 + k];
    }
    for (int i = tid; i < 261; i += 256)
        ipl[i] = interp_T(inten, b, l0 - 3 + i);
    __syncthreads();
    for (int i = tid; i < 260; i += 256) {
        int p = l0 - 2 + i;
        int pr = refl(p);
        float cur = ipl[pr - l0 + 3];
        float prev = (pr == 0) ? cur : ipl[pr - 1 - l0 + 3];
        float diff = cur - prev;
        float ar = interp_T(attack, b, pr);
        float enh = fminf(fmaxf(cur + (diff > 0.1f ? ar * 0.3f : 0.0f), 0.0f), 1.0f);
        gp[i] = (diff > 0.0f) ? enh : cur;
    }
    __syncthreads();
    const int l = l0 + tid;
    int i0, i1; float w;
    interp_idx(l, i0, i1, w);
    int d0 = min(max(i0 - f0, 0), 3);
    int d1 = min(max(i1 - f0, 0), 3);
    float a0 = 0.0f, a1 = 0.0f;
#pragma unroll
    for (int k = 0; k < 31; ++k) {
        float xk = xs[tid + k];
        a0 += xk * hl[d0][k];
        a1 += xk * hl[d1][k];
    }
    float shaped = (1.0f - w) * a0 + w * a1;
    float g5 = (gp[tid] + gp[tid + 1] + gp[tid + 2] + gp[tid + 3] + gp[tid + 4]) * 0.2f;
    out[b * L + l] = shaped * g5;
    out[B * L + b * L + l] = g5;
}

extern "C" void kernel_launch(void* const* d_in, const int* in_sizes, int n_in,
                              void* d_out, int out_size, void* d_ws, size_t ws_size,
                              hipStream_t stream) {
    const float* cond  = (const float*)d_in[0];
    const float* wn    = (const float*)d_in[1];
    const float* np_w1 = (const float*)d_in[2];
    const float* np_b1 = (const float*)d_in[3];
    const float* np_w2 = (const float*)d_in[4];
    const float* np_b2 = (const float*)d_in[5];
    const float* np_w3 = (const float*)d_in[6];
    const float* np_b3 = (const float*)d_in[7];
    const float* ss_w1 = (const float*)d_in[8];
    const float* ss_b1 = (const float*)d_in[9];
    const float* ss_w2 = (const float*)d_in[10];
    const float* ss_b2 = (const float*)d_in[11];
    const float* fb_w  = (const float*)d_in[12];
    const float* nt_w  = (const float*)d_in[13];

    float* ws   = (float*)d_ws;
    float* bufA = ws;                          // h1 (8*256*800) then reused for g (8*128*800)
    float* bufB = bufA + 8 * 256 * 800;        // h2 (8*256*800) then reused for filt (8*L? no: 8*192000 <= 1638400)
    float* band   = bufB + 8 * 256 * 800;      // 153600
    float* attack = band + 8 * NB * 800;       // 6400
    float* inten  = attack + 8 * 800;          // 6400
    float* ntw    = inten + 8 * 800;           // 25600
    float* g_all  = ntw + 8 * 4 * 800;         // 403200
    float* h_all  = g_all + 8 * 800 * 63;      // 198400
    float* wT1    = h_all + 8 * 800 * 31;      // 98304
    float* wT2    = wT1 + 98304;               // 196608
    float* wTs    = wT2 + 196608;              // 49152
    float* h1 = bufA;
    float* h2 = bufB;
    float* g  = bufA;       // after np2 consumed h1
    float* filt = bufB;     // after np3 consumed h2
    float* out = (float*)d_out;

    k_tw<<<1344, 256, 0, stream>>>(np_w1, np_w2, ss_w1, wT1, wT2, wTs);
    k_conv3<128, 256><<<dim3(50, 8), 256, 0, stream>>>(cond, wT1, np_b1, h1);
    k_conv3<256, 256><<<dim3(50, 8), 256, 0, stream>>>(h1, wT2, np_b2, h2);
    k_np3<<<dim3(25, 8), 256, 0, stream>>>(h2, np_w3, np_b3, band, attack, inten);
    k_conv3<128, 128><<<dim3(50, 8), 128, 0, stream>>>(cond, wTs, ss_b1, g);
    k_ss2<<<dim3(25, 8), 256, 0, stream>>>(g, ss_w2, ss_b2, ntw);
    k_gfilt<<<(B * T * 63 + 255) / 256, 256, 0, stream>>>(ntw, nt_w, g_all);
    k_hfilt<<<(B * T * 31 + 255) / 256, 256, 0, stream>>>(band, fb_w, h_all);
    k_filter<<<dim3(750, 8), 256, 0, stream>>>(wn, g_all, filt);
    k_out<<<dim3(750, 8), 256, 0, stream>>>(filt, h_all, attack, inten, out);
}

// Round 3
// 244.364 us; speedup vs baseline: 1.8887x; 1.3882x over previous
//
#include <hip/hip_runtime.h>
#include <math.h>

static constexpr int B  = 8;
static constexpr int T  = 800;
static constexpr int L  = 192000;
static constexpr int NB = 24;
static constexpr float SCALE = 800.0f / 192000.0f;  // T/L

typedef __bf16 bf8 __attribute__((ext_vector_type(8)));
typedef float  f4  __attribute__((ext_vector_type(4)));

__device__ __forceinline__ float sigf(float x) { return 1.0f / (1.0f + __expf(-x)); }
__device__ __forceinline__ float leaky(float x) { return x >= 0.0f ? x : 0.1f * x; }
__device__ __forceinline__ unsigned short f2bf(float f) {
    unsigned u = __float_as_uint(f);
    u = u + 0x7FFFu + ((u >> 16) & 1u);
    return (unsigned short)(u >> 16);
}
__device__ __forceinline__ float bf2f(unsigned short b) {
    return __uint_as_float(((unsigned)b) << 16);
}

__device__ __forceinline__ void interp_idx(int l, int& i0, int& i1, float& w) {
    float pos = ((float)l + 0.5f) * SCALE - 0.5f;
    pos = fminf(fmaxf(pos, 0.0f), (float)(T - 1));
    i0 = (int)pos;                 // pos >= 0, trunc == floor
    i1 = min(i0 + 1, T - 1);
    w = pos - (float)i0;
}

// ---------------- weight transpose+cast: [cout][cin][3] f32 -> [tap][cout][cin] bf16 ----------------
__global__ __launch_bounds__(256) void k_twm(const float* __restrict__ w1,
                                             const float* __restrict__ w2,
                                             const float* __restrict__ wss,
                                             unsigned short* __restrict__ wT1,
                                             unsigned short* __restrict__ wT2,
                                             unsigned short* __restrict__ wTs) {
    int idx = blockIdx.x * 256 + threadIdx.x;
    if (idx < 98304) {                        // np_w1 [256][128][3]
        int tap = idx / (256 * 128), r = idx % (256 * 128);
        int cout = r / 128, cin = r % 128;
        wT1[idx] = f2bf(w1[(cout * 128 + cin) * 3 + tap]);
    } else if (idx < 98304 + 196608) {        // np_w2 [256][256][3]
        int j = idx - 98304;
        int tap = j / (256 * 256), r = j % (256 * 256);
        int cout = r / 256, cin = r % 256;
        wT2[j] = f2bf(w2[(cout * 256 + cin) * 3 + tap]);
    } else if (idx < 98304 + 196608 + 49152) {// ss_w1 [128][128][3]
        int j = idx - 294912;
        int tap = j / (128 * 128), r = j % (128 * 128);
        int cout = r / 128, cin = r % 128;
        wTs[j] = f2bf(wss[(cout * 128 + cin) * 3 + tap]);
    }
}

// ---------------- MFMA k=3 conv, pad=1, leaky; out bf16 ----------------
// Y[cout][t0..t0+16) = leaky( sum_tap W_tap * X[:, t+tap-1] + bias )
template<int CIN, int COUT, bool INBF>
__global__ __launch_bounds__(256) void k_conv3m(const void* __restrict__ xin,
                                                const unsigned short* __restrict__ wT,
                                                const float* __restrict__ bias,
                                                unsigned short* __restrict__ y) {
    constexpr int CINP = CIN + 8;             // pad 16B -> 4-bank row stagger
    constexpr int MT = COUT / 64;             // 16-row m-tiles per wave
    __shared__ unsigned short xs[18 * CINP];  // xs[t_local][cin], bf16
    const int b = blockIdx.y;
    const int t0 = blockIdx.x * 16;
    const int tid = threadIdx.x;
    const float* xf = (const float*)xin;
    const unsigned short* xb = (const unsigned short*)xin;
    for (int i = tid; i < 18 * CIN; i += 256) {
        int cin = i / 18, tr = i % 18;
        int t = t0 + tr - 1;
        unsigned short bits = 0;
        if (t >= 0 && t < T) {
            if (INBF) bits = xb[(b * CIN + cin) * T + t];
            else      bits = f2bf(xf[(b * CIN + cin) * T + t]);
        }
        xs[tr * CINP + cin] = bits;
    }
    __syncthreads();
    const int wave = tid >> 6, lane = tid & 63;
    const int coutb = wave * (COUT / 4);
    const int nfr = lane & 15;            // m-index for A-frag, n-index for B-frag
    const int ko8 = (lane >> 4) * 8;      // k-octet
    f4 acc[MT] = {};
#pragma unroll
    for (int tap = 0; tap < 3; ++tap) {
        const unsigned short* wp = wT + ((tap * COUT + coutb + nfr) * CIN + ko8);
        const unsigned short* xp = xs + (nfr + tap) * CINP + ko8;
#pragma unroll 2
        for (int kc = 0; kc < CIN; kc += 32) {
            bf8 bv = *reinterpret_cast<const bf8*>(xp + kc);
#pragma unroll
            for (int m = 0; m < MT; ++m) {
                bf8 av = *reinterpret_cast<const bf8*>(wp + m * 16 * CIN + kc);
                acc[m] = __builtin_amdgcn_mfma_f32_16x16x32_bf16(av, bv, acc[m], 0, 0, 0);
            }
        }
    }
    const int rb = (lane >> 4) * 4;       // C/D: row=(lane>>4)*4+reg, col=lane&15
    const int tcol = lane & 15;
#pragma unroll
    for (int m = 0; m < MT; ++m) {
#pragma unroll
        for (int r = 0; r < 4; ++r) {
            int cout = coutb + m * 16 + rb + r;
            float v = leaky(acc[m][r] + bias[cout]);
            y[(b * COUT + cout) * T + t0 + tcol] = f2bf(v);
        }
    }
}

// ---------------- noise predictor head: 256 -> 27 (1x1) + sigmoids (bf16 in) ----------------
__global__ __launch_bounds__(256) void k_np3(const unsigned short* __restrict__ h2,
                                             const float* __restrict__ w3,
                                             const float* __restrict__ b3,
                                             float* __restrict__ band,
                                             float* __restrict__ attack,
                                             float* __restrict__ inten) {
    __shared__ float ps[32][8][27];
    const int b = blockIdx.y;
    const int t0 = blockIdx.x * 32;
    const int tid = threadIdx.x;
    const int tl = tid >> 3, ch = tid & 7;
    const int t = t0 + tl;
    float acc[27];
#pragma unroll
    for (int c = 0; c < 27; ++c) acc[c] = 0.0f;
    for (int ci = 0; ci < 32; ++ci) {
        int cin = ch * 32 + ci;
        float v = bf2f(h2[(b * 256 + cin) * T + t]);
#pragma unroll
        for (int c = 0; c < 27; ++c) acc[c] += v * w3[c * 256 + cin];
    }
#pragma unroll
    for (int c = 0; c < 27; ++c) ps[tl][ch][c] = acc[c];
    __syncthreads();
    for (int i = tid; i < 32 * 27; i += 256) {
        int tt = i / 27, c = i % 27;
        float s = b3[c];
#pragma unroll
        for (int j = 0; j < 8; ++j) s += ps[tt][j][c];
        int gt = t0 + tt;
        if (c < NB) band[(b * NB + c) * T + gt] = sigf(s);
        else if (c == 24) attack[b * T + gt] = sigf(s) * 10.0f;
        else if (c == 26) inten[b * T + gt] = sigf(s);
    }
}

// ---------------- spectral shaper head: 128 -> 4 (1x1) + softmax (bf16 in) ----------------
__global__ __launch_bounds__(256) void k_ss2(const unsigned short* __restrict__ g,
                                             const float* __restrict__ w2,
                                             const float* __restrict__ b2,
                                             float* __restrict__ ntw) {
    __shared__ float ps[32][8][4];
    __shared__ float rs[32][4];
    const int b = blockIdx.y;
    const int t0 = blockIdx.x * 32;
    const int tid = threadIdx.x;
    const int tl = tid >> 3, ch = tid & 7;
    const int t = t0 + tl;
    float acc[4] = {0.f, 0.f, 0.f, 0.f};
    for (int ci = 0; ci < 16; ++ci) {
        int cin = ch * 16 + ci;
        float v = bf2f(g[(b * 128 + cin) * T + t]);
#pragma unroll
        for (int c = 0; c < 4; ++c) acc[c] += v * w2[c * 128 + cin];
    }
#pragma unroll
    for (int c = 0; c < 4; ++c) ps[tl][ch][c] = acc[c];
    __syncthreads();
    if (tid < 128) {
        int tt = tid >> 2, c = tid & 3;
        float s = b2[c];
#pragma unroll
        for (int j = 0; j < 8; ++j) s += ps[tt][j][c];
        rs[tt][c] = s;
    }
    __syncthreads();
    if (tid < 32) {
        float a0 = rs[tid][0], a1 = rs[tid][1], a2 = rs[tid][2], a3 = rs[tid][3];
        float m = fmaxf(fmaxf(a0, a1), fmaxf(a2, a3));
        float e0 = __expf(a0 - m), e1 = __expf(a1 - m), e2 = __expf(a2 - m), e3 = __expf(a3 - m);
        float inv = 1.0f / (e0 + e1 + e2 + e3);
        int gt = t0 + tid;
        ntw[(b * 4 + 0) * T + gt] = e0 * inv;
        ntw[(b * 4 + 1) * T + gt] = e1 * inv;
        ntw[(b * 4 + 2) * T + gt] = e2 * inv;
        ntw[(b * 4 + 3) * T + gt] = e3 * inv;
    }
}

// ---------------- per-frame effective filters (gfilt + hfilt merged) ----------------
__global__ __launch_bounds__(256) void k_eff(const float* __restrict__ ntw,
                                             const float* __restrict__ ntf,
                                             const float* __restrict__ band,
                                             const float* __restrict__ fbw,
                                             float* __restrict__ g_all,
                                             float* __restrict__ h_all) {
    int idx = blockIdx.x * 256 + threadIdx.x;
    if (idx < B * T * 63) {
        int b = idx / (T * 63), r = idx % (T * 63);
        int f = r / 63, k = r % 63;
        float s = 0.0f;
#pragma unroll
        for (int c = 0; c < 4; ++c)
            s += ntf[c * 63 + k] * ntw[(b * 4 + c) * T + f];
        g_all[idx] = s;
    } else {
        int j = idx - B * T * 63;
        if (j < B * T * 31) {
            int b = j / (T * 31), r = j % (T * 31);
            int f = r / 31, k = r % 31;
            float s = 0.0f;
#pragma unroll
            for (int c = 0; c < NB; ++c)
                s += fbw[c * 31 + k] * band[(b * NB + c) * T + f];
            h_all[j] = s;
        }
    }
}

// ---------------- noise-type FIR + mix, via frame-lerped filters ----------------
__global__ __launch_bounds__(256) void k_filter(const float* __restrict__ wn,
                                                const float* __restrict__ g_all,
                                                float* __restrict__ filt) {
    __shared__ float xs[318];
    __shared__ float gl[4][63];
    const int b = blockIdx.y;
    const int l0 = blockIdx.x * 256;
    const int tid = threadIdx.x;
    for (int i = tid; i < 318; i += 256) {
        int gp = l0 - 31 + i;
        xs[i] = (gp >= 0 && gp < L) ? wn[b * L + gp] : 0.0f;
    }
    int f0, f1u; float wu;
    interp_idx(l0, f0, f1u, wu);
    if (tid < 252) {
        int j = tid / 63, k = tid % 63;
        int f = min(f0 + j, T - 1);
        gl[j][k] = g_all[(b * T + f) * 63 + k];
    }
    __syncthreads();
    const int l = l0 + tid;
    int i0, i1; float w;
    interp_idx(l, i0, i1, w);
    int d0 = min(max(i0 - f0, 0), 3);
    int d1 = min(max(i1 - f0, 0), 3);
    float a0 = 0.0f, a1 = 0.0f;
#pragma unroll
    for (int k = 0; k < 63; ++k) {
        float xk = xs[tid + k];
        a0 += xk * gl[d0][k];
        a1 += xk * gl[d1][k];
    }
    filt[b * L + l] = (1.0f - w) * a0 + w * a1;
}

// ---------------- filterbank mix + gate + outputs ----------------
__device__ __forceinline__ float interp_T(const float* __restrict__ a, int b, int p) {
    int i0, i1; float w;
    interp_idx(p, i0, i1, w);
    return a[b * T + i0] * (1.0f - w) + a[b * T + i1] * w;
}

__device__ __forceinline__ int refl(int p) {
    return p < 0 ? -p : (p >= L ? 2 * L - 2 - p : p);
}

__global__ __launch_bounds__(256) void k_out(const float* __restrict__ filt,
                                             const float* __restrict__ h_all,
                                             const float* __restrict__ attack,
                                             const float* __restrict__ inten,
                                             float* __restrict__ out) {
    __shared__ float xs[286];
    __shared__ float hl[4][31];
    __shared__ float ipl[261];   // intensity_up(l0-3+i)
    __shared__ float gp[260];    // gate_pre(l0-2+i) (reflected)
    const int b = blockIdx.y;
    const int l0 = blockIdx.x * 256;
    const int tid = threadIdx.x;
    for (int i = tid; i < 286; i += 256) {
        int p = l0 - 15 + i;
        xs[i] = (p >= 0 && p < L) ? filt[b * L + p] : 0.0f;
    }
    int f0, f1u; float wu;
    interp_idx(l0, f0, f1u, wu);
    if (tid < 124) {
        int j = tid / 31, k = tid % 31;
        int f = min(f0 + j, T - 1);
        hl[j][k] = h_all[(b * T + f) * 31 + k];
    }
    for (int i = tid; i < 261; i += 256)
        ipl[i] = interp_T(inten, b, l0 - 3 + i);
    __syncthreads();
    for (int i = tid; i < 260; i += 256) {
        int p = l0 - 2 + i;
        int pr = refl(p);
        float cur = ipl[pr - l0 + 3];
        float prev = (pr == 0) ? cur : ipl[pr - 1 - l0 + 3];
        float diff = cur - prev;
        float ar = interp_T(attack, b, pr);
        float enh = fminf(fmaxf(cur + (diff > 0.1f ? ar * 0.3f : 0.0f), 0.0f), 1.0f);
        gp[i] = (diff > 0.0f) ? enh : cur;
    }
    __syncthreads();
    const int l = l0 + tid;
    int i0, i1; float w;
    interp_idx(l, i0, i1, w);
    int d0 = min(max(i0 - f0, 0), 3);
    int d1 = min(max(i1 - f0, 0), 3);
    float a0 = 0.0f, a1 = 0.0f;
#pragma unroll
    for (int k = 0; k < 31; ++k) {
        float xk = xs[tid + k];
        a0 += xk * hl[d0][k];
        a1 += xk * hl[d1][k];
    }
    float shaped = (1.0f - w) * a0 + w * a1;
    float g5 = (gp[tid] + gp[tid + 1] + gp[tid + 2] + gp[tid + 3] + gp[tid + 4]) * 0.2f;
    out[b * L + l] = shaped * g5;
    out[B * L + b * L + l] = g5;
}

extern "C" void kernel_launch(void* const* d_in, const int* in_sizes, int n_in,
                              void* d_out, int out_size, void* d_ws, size_t ws_size,
                              hipStream_t stream) {
    const float* cond  = (const float*)d_in[0];
    const float* wn    = (const float*)d_in[1];
    const float* np_w1 = (const float*)d_in[2];
    const float* np_b1 = (const float*)d_in[3];
    const float* np_w2 = (const float*)d_in[4];
    const float* np_b2 = (const float*)d_in[5];
    const float* np_w3 = (const float*)d_in[6];
    const float* np_b3 = (const float*)d_in[7];
    const float* ss_w1 = (const float*)d_in[8];
    const float* ss_b1 = (const float*)d_in[9];
    const float* ss_w2 = (const float*)d_in[10];
    const float* ss_b2 = (const float*)d_in[11];
    const float* fb_w  = (const float*)d_in[12];
    const float* nt_w  = (const float*)d_in[13];

    char* p = (char*)d_ws;
    unsigned short* wT1 = (unsigned short*)p; p += 196608;   // [3][256][128] bf16
    unsigned short* wT2 = (unsigned short*)p; p += 393216;   // [3][256][256] bf16
    unsigned short* wTs = (unsigned short*)p; p += 98304;    // [3][128][128] bf16
    unsigned short* h1  = (unsigned short*)p; p += 3276800;  // [8][256][800] bf16 (reused for g)
    unsigned short* h2  = (unsigned short*)p; p += 3276800;  // [8][256][800] bf16
    float* filt   = (float*)p; p += 6144000;                 // [8][192000]
    float* band   = (float*)p; p += 614400;                  // [8][24][800]
    float* attack = (float*)p; p += 25600;                   // [8][800]
    float* inten  = (float*)p; p += 25600;                   // [8][800]
    float* ntw    = (float*)p; p += 102400;                  // [8][4][800]
    float* g_all  = (float*)p; p += 1612800;                 // [8][800][63]
    float* h_all  = (float*)p; p += 793600;                  // [8][800][31]
    unsigned short* g = h1;   // h1 dead after np2
    float* out = (float*)d_out;

    k_twm<<<1344, 256, 0, stream>>>(np_w1, np_w2, ss_w1, wT1, wT2, wTs);
    k_conv3m<128, 256, false><<<dim3(50, 8), 256, 0, stream>>>(cond, wT1, np_b1, h1);
    k_conv3m<256, 256, true ><<<dim3(50, 8), 256, 0, stream>>>(h1, wT2, np_b2, h2);
    k_np3<<<dim3(25, 8), 256, 0, stream>>>(h2, np_w3, np_b3, band, attack, inten);
    k_conv3m<128, 128, false><<<dim3(50, 8), 256, 0, stream>>>(cond, wTs, ss_b1, g);
    k_ss2<<<dim3(25, 8), 256, 0, stream>>>(g, ss_w2, ss_b2, ntw);
    k_eff<<<2350, 256, 0, stream>>>(ntw, nt_w, band, fb_w, g_all, h_all);
    k_filter<<<dim3(750, 8), 256, 0, stream>>>(wn, g_all, filt);
    k_out<<<dim3(750, 8), 256, 0, stream>>>(filt, h_all, attack, inten, out);
}

// Round 4
// 226.907 us; speedup vs baseline: 2.0340x; 1.0769x over previous
//
#include <hip/hip_runtime.h>
#include <math.h>

static constexpr int B  = 8;
static constexpr int T  = 800;
static constexpr int L  = 192000;
static constexpr int NB = 24;
static constexpr float SCALE = 800.0f / 192000.0f;  // T/L

typedef __bf16 bf8 __attribute__((ext_vector_type(8)));
typedef float  f4  __attribute__((ext_vector_type(4)));

__device__ __forceinline__ float sigf(float x) { return 1.0f / (1.0f + __expf(-x)); }
__device__ __forceinline__ float leaky(float x) { return x >= 0.0f ? x : 0.1f * x; }
__device__ __forceinline__ unsigned short f2bf(float f) {
    unsigned u = __float_as_uint(f);
    u = u + 0x7FFFu + ((u >> 16) & 1u);
    return (unsigned short)(u >> 16);
}
__device__ __forceinline__ float bf2f(unsigned short b) {
    return __uint_as_float(((unsigned)b) << 16);
}

__device__ __forceinline__ void interp_idx(int l, int& i0, int& i1, float& w) {
    float pos = ((float)l + 0.5f) * SCALE - 0.5f;
    pos = fminf(fmaxf(pos, 0.0f), (float)(T - 1));
    i0 = (int)pos;                 // pos >= 0, trunc == floor
    i1 = min(i0 + 1, T - 1);
    w = pos - (float)i0;
}

// ---------------- weight transpose+cast: [cout][cin][3] f32 -> [tap][cout][cin] bf16 ----------------
__global__ __launch_bounds__(256) void k_twm(const float* __restrict__ w1,
                                             const float* __restrict__ w2,
                                             const float* __restrict__ wss,
                                             unsigned short* __restrict__ wT1,
                                             unsigned short* __restrict__ wT2,
                                             unsigned short* __restrict__ wTs) {
    int idx = blockIdx.x * 256 + threadIdx.x;
    if (idx < 98304) {                        // np_w1 [256][128][3]
        int tap = idx / (256 * 128), r = idx % (256 * 128);
        int cout = r / 128, cin = r % 128;
        wT1[idx] = f2bf(w1[(cout * 128 + cin) * 3 + tap]);
    } else if (idx < 98304 + 196608) {        // np_w2 [256][256][3]
        int j = idx - 98304;
        int tap = j / (256 * 256), r = j % (256 * 256);
        int cout = r / 256, cin = r % 256;
        wT2[j] = f2bf(w2[(cout * 256 + cin) * 3 + tap]);
    } else if (idx < 98304 + 196608 + 49152) {// ss_w1 [128][128][3]
        int j = idx - 294912;
        int tap = j / (128 * 128), r = j % (128 * 128);
        int cout = r / 128, cin = r % 128;
        wTs[j] = f2bf(wss[(cout * 128 + cin) * 3 + tap]);
    }
}

// ---------------- MFMA k=3 conv, pad=1, leaky; out bf16 ----------------
template<int CIN, int COUT, bool INBF>
__global__ __launch_bounds__(256) void k_conv3m(const void* __restrict__ xin,
                                                const unsigned short* __restrict__ wT,
                                                const float* __restrict__ bias,
                                                unsigned short* __restrict__ y) {
    constexpr int CINP = CIN + 8;
    constexpr int MT = COUT / 64;
    __shared__ unsigned short xs[18 * CINP];  // xs[t_local][cin], bf16
    const int b = blockIdx.y;
    const int t0 = blockIdx.x * 16;
    const int tid = threadIdx.x;
    const float* xf = (const float*)xin;
    const unsigned short* xb = (const unsigned short*)xin;
    for (int i = tid; i < 18 * CIN; i += 256) {
        int cin = i / 18, tr = i % 18;
        int t = t0 + tr - 1;
        unsigned short bits = 0;
        if (t >= 0 && t < T) {
            if (INBF) bits = xb[(b * CIN + cin) * T + t];
            else      bits = f2bf(xf[(b * CIN + cin) * T + t]);
        }
        xs[tr * CINP + cin] = bits;
    }
    __syncthreads();
    const int wave = tid >> 6, lane = tid & 63;
    const int coutb = wave * (COUT / 4);
    const int nfr = lane & 15;
    const int ko8 = (lane >> 4) * 8;
    f4 acc[MT] = {};
#pragma unroll
    for (int tap = 0; tap < 3; ++tap) {
        const unsigned short* wp = wT + ((tap * COUT + coutb + nfr) * CIN + ko8);
        const unsigned short* xp = xs + (nfr + tap) * CINP + ko8;
#pragma unroll 2
        for (int kc = 0; kc < CIN; kc += 32) {
            bf8 bv = *reinterpret_cast<const bf8*>(xp + kc);
#pragma unroll
            for (int m = 0; m < MT; ++m) {
                bf8 av = *reinterpret_cast<const bf8*>(wp + m * 16 * CIN + kc);
                acc[m] = __builtin_amdgcn_mfma_f32_16x16x32_bf16(av, bv, acc[m], 0, 0, 0);
            }
        }
    }
    const int rb = (lane >> 4) * 4;
    const int tcol = lane & 15;
#pragma unroll
    for (int m = 0; m < MT; ++m) {
#pragma unroll
        for (int r = 0; r < 4; ++r) {
            int cout = coutb + m * 16 + rb + r;
            float v = leaky(acc[m][r] + bias[cout]);
            y[(b * COUT + cout) * T + t0 + tcol] = f2bf(v);
        }
    }
}

// ---------------- np head partials: chunk of 64 cin -> 27 partial sums ----------------
// part_np[((chunk*B + b)*27 + c)*T + t]
__global__ __launch_bounds__(256) void k_np_part(const unsigned short* __restrict__ h2,
                                                 const float* __restrict__ w3,
                                                 float* __restrict__ part) {
    const int t = blockIdx.x * 256 + threadIdx.x;
    const int chunk = blockIdx.y;
    const int b = blockIdx.z;
    if (t >= T) return;
    const int c0 = chunk * 64;
    float acc[27];
#pragma unroll
    for (int c = 0; c < 27; ++c) acc[c] = 0.0f;
    for (int ci = 0; ci < 64; ++ci) {
        int cin = c0 + ci;
        float v = bf2f(h2[(b * 256 + cin) * T + t]);
#pragma unroll
        for (int c = 0; c < 27; ++c) acc[c] += v * w3[c * 256 + cin];
    }
    float* pp = part + ((chunk * B + b) * 27) * T + t;
#pragma unroll
    for (int c = 0; c < 27; ++c) pp[c * T] = acc[c];
}

// ---------------- ss head partials: chunk of 64 cin -> 4 partial sums ----------------
// part_ss[((chunk*B + b)*4 + c)*T + t]
__global__ __launch_bounds__(256) void k_ss_part(const unsigned short* __restrict__ g,
                                                 const float* __restrict__ w2,
                                                 float* __restrict__ part) {
    const int t = blockIdx.x * 256 + threadIdx.x;
    const int chunk = blockIdx.y;
    const int b = blockIdx.z;
    if (t >= T) return;
    const int c0 = chunk * 64;
    float acc[4] = {0.f, 0.f, 0.f, 0.f};
    for (int ci = 0; ci < 64; ++ci) {
        int cin = c0 + ci;
        float v = bf2f(g[(b * 128 + cin) * T + t]);
#pragma unroll
        for (int c = 0; c < 4; ++c) acc[c] += v * w2[c * 128 + cin];
    }
    float* pp = part + ((chunk * B + b) * 4) * T + t;
#pragma unroll
    for (int c = 0; c < 4; ++c) pp[c * T] = acc[c];
}

// ---------------- finalize heads: sigmoid/softmax + effective filters ----------------
// g_all[b][63][T], h_all[b][31][T]  (k-major rows -> coalesced writes over f)
__global__ __launch_bounds__(256) void k_finalize(const float* __restrict__ part_np,
                                                  const float* __restrict__ part_ss,
                                                  const float* __restrict__ b3,
                                                  const float* __restrict__ b2,
                                                  const float* __restrict__ ntf,
                                                  const float* __restrict__ fbw,
                                                  float* __restrict__ g_all,
                                                  float* __restrict__ h_all,
                                                  float* __restrict__ attack,
                                                  float* __restrict__ inten) {
    const int idx = blockIdx.x * 256 + threadIdx.x;
    if (idx >= B * T) return;
    const int b = idx / T, f = idx % T;

    float bnd[NB];
    float s24 = 0, s26 = 0;
#pragma unroll
    for (int c = 0; c < 27; ++c) {
        float s = b3[c];
#pragma unroll
        for (int ch = 0; ch < 4; ++ch)
            s += part_np[((ch * B + b) * 27 + c) * T + f];
        if (c < NB) bnd[c] = sigf(s);
        else if (c == 24) s24 = s;
        else if (c == 26) s26 = s;
    }
    attack[b * T + f] = sigf(s24) * 10.0f;
    inten[b * T + f] = sigf(s26);

    float ss[4];
#pragma unroll
    for (int c = 0; c < 4; ++c) {
        float s = b2[c];
#pragma unroll
        for (int ch = 0; ch < 2; ++ch)
            s += part_ss[((ch * B + b) * 4 + c) * T + f];
        ss[c] = s;
    }
    float m = fmaxf(fmaxf(ss[0], ss[1]), fmaxf(ss[2], ss[3]));
    float e0 = __expf(ss[0] - m), e1 = __expf(ss[1] - m);
    float e2 = __expf(ss[2] - m), e3 = __expf(ss[3] - m);
    float inv = 1.0f / (e0 + e1 + e2 + e3);
    float nw0 = e0 * inv, nw1 = e1 * inv, nw2 = e2 * inv, nw3 = e3 * inv;

#pragma unroll
    for (int k = 0; k < 63; ++k) {
        float s = nw0 * ntf[k] + nw1 * ntf[63 + k] + nw2 * ntf[126 + k] + nw3 * ntf[189 + k];
        g_all[(b * 63 + k) * T + f] = s;
    }
#pragma unroll
    for (int k = 0; k < 31; ++k) {
        float s = 0.0f;
#pragma unroll
        for (int c = 0; c < NB; ++c) s += bnd[c] * fbw[c * 31 + k];
        h_all[(b * 31 + k) * T + f] = s;
    }
}

// ---------------- noise-type FIR + mix, via frame-lerped filters ----------------
__global__ __launch_bounds__(256) void k_filter(const float* __restrict__ wn,
                                                const float* __restrict__ g_all,
                                                float* __restrict__ filt) {
    __shared__ float xs[318];
    __shared__ float gl[4][63];
    const int b = blockIdx.y;
    const int l0 = blockIdx.x * 256;
    const int tid = threadIdx.x;
    for (int i = tid; i < 318; i += 256) {
        int gp = l0 - 31 + i;
        xs[i] = (gp >= 0 && gp < L) ? wn[b * L + gp] : 0.0f;
    }
    int f0, f1u; float wu;
    interp_idx(l0, f0, f1u, wu);
    if (tid < 252) {
        int j = tid / 63, k = tid % 63;
        int f = min(f0 + j, T - 1);
        gl[j][k] = g_all[(b * 63 + k) * T + f];
    }
    __syncthreads();
    const int l = l0 + tid;
    int i0, i1; float w;
    interp_idx(l, i0, i1, w);
    int d0 = min(max(i0 - f0, 0), 3);
    int d1 = min(max(i1 - f0, 0), 3);
    float a0 = 0.0f, a1 = 0.0f;
#pragma unroll
    for (int k = 0; k < 63; ++k) {
        float xk = xs[tid + k];
        a0 += xk * gl[d0][k];
        a1 += xk * gl[d1][k];
    }
    filt[b * L + l] = (1.0f - w) * a0 + w * a1;
}

// ---------------- filterbank mix + gate + outputs ----------------
__device__ __forceinline__ float interp_T(const float* __restrict__ a, int b, int p) {
    int i0, i1; float w;
    interp_idx(p, i0, i1, w);
    return a[b * T + i0] * (1.0f - w) + a[b * T + i1] * w;
}

__device__ __forceinline__ int refl(int p) {
    return p < 0 ? -p : (p >= L ? 2 * L - 2 - p : p);
}

__global__ __launch_bounds__(256) void k_out(const float* __restrict__ filt,
                                             const float* __restrict__ h_all,
                                             const float* __restrict__ attack,
                                             const float* __restrict__ inten,
                                             float* __restrict__ out) {
    __shared__ float xs[286];
    __shared__ float hl[4][31];
    __shared__ float ipl[261];   // intensity_up(l0-3+i)
    __shared__ float gp[260];    // gate_pre(l0-2+i) (reflected)
    const int b = blockIdx.y;
    const int l0 = blockIdx.x * 256;
    const int tid = threadIdx.x;
    for (int i = tid; i < 286; i += 256) {
        int p = l0 - 15 + i;
        xs[i] = (p >= 0 && p < L) ? filt[b * L + p] : 0.0f;
    }
    int f0, f1u; float wu;
    interp_idx(l0, f0, f1u, wu);
    if (tid < 124) {
        int j = tid / 31, k = tid % 31;
        int f = min(f0 + j, T - 1);
        hl[j][k] = h_all[(b * 31 + k) * T + f];
    }
    for (int i = tid; i < 261; i += 256)
        ipl[i] = interp_T(inten, b, l0 - 3 + i);
    __syncthreads();
    for (int i = tid; i < 260; i += 256) {
        int p = l0 - 2 + i;
        int pr = refl(p);
        float cur = ipl[pr - l0 + 3];
        float prev = (pr == 0) ? cur : ipl[pr - 1 - l0 + 3];
        float diff = cur - prev;
        float ar = interp_T(attack, b, pr);
        float enh = fminf(fmaxf(cur + (diff > 0.1f ? ar * 0.3f : 0.0f), 0.0f), 1.0f);
        gp[i] = (diff > 0.0f) ? enh : cur;
    }
    __syncthreads();
    const int l = l0 + tid;
    int i0, i1; float w;
    interp_idx(l, i0, i1, w);
    int d0 = min(max(i0 - f0, 0), 3);
    int d1 = min(max(i1 - f0, 0), 3);
    float a0 = 0.0f, a1 = 0.0f;
#pragma unroll
    for (int k = 0; k < 31; ++k) {
        float xk = xs[tid + k];
        a0 += xk * hl[d0][k];
        a1 += xk * hl[d1][k];
    }
    float shaped = (1.0f - w) * a0 + w * a1;
    float g5 = (gp[tid] + gp[tid + 1] + gp[tid + 2] + gp[tid + 3] + gp[tid + 4]) * 0.2f;
    out[b * L + l] = shaped * g5;
    out[B * L + b * L + l] = g5;
}

extern "C" void kernel_launch(void* const* d_in, const int* in_sizes, int n_in,
                              void* d_out, int out_size, void* d_ws, size_t ws_size,
                              hipStream_t stream) {
    const float* cond  = (const float*)d_in[0];
    const float* wn    = (const float*)d_in[1];
    const float* np_w1 = (const float*)d_in[2];
    const float* np_b1 = (const float*)d_in[3];
    const float* np_w2 = (const float*)d_in[4];
    const float* np_b2 = (const float*)d_in[5];
    const float* np_w3 = (const float*)d_in[6];
    const float* np_b3 = (const float*)d_in[7];
    const float* ss_w1 = (const float*)d_in[8];
    const float* ss_b1 = (const float*)d_in[9];
    const float* ss_w2 = (const float*)d_in[10];
    const float* ss_b2 = (const float*)d_in[11];
    const float* fb_w  = (const float*)d_in[12];
    const float* nt_w  = (const float*)d_in[13];

    char* p = (char*)d_ws;
    unsigned short* wT1 = (unsigned short*)p; p += 196608;   // [3][256][128] bf16
    unsigned short* wT2 = (unsigned short*)p; p += 393216;   // [3][256][256] bf16
    unsigned short* wTs = (unsigned short*)p; p += 98304;    // [3][128][128] bf16
    unsigned short* h1  = (unsigned short*)p; p += 3276800;  // [8][256][800] bf16 (reused for g)
    unsigned short* h2  = (unsigned short*)p; p += 3276800;  // [8][256][800] bf16
    float* filt    = (float*)p; p += 6144000;                // [8][192000]
    float* part_np = (float*)p; p += 2764800;                // [4][8][27][800]
    float* part_ss = (float*)p; p += 204800;                 // [2][8][4][800]
    float* attack  = (float*)p; p += 25600;                  // [8][800]
    float* inten   = (float*)p; p += 25600;                  // [8][800]
    float* g_all   = (float*)p; p += 1612800;                // [8][63][800]
    float* h_all   = (float*)p; p += 793600;                 // [8][31][800]
    unsigned short* g = h1;   // h1 dead after np2
    float* out = (float*)d_out;

    k_twm<<<1344, 256, 0, stream>>>(np_w1, np_w2, ss_w1, wT1, wT2, wTs);
    k_conv3m<128, 256, false><<<dim3(50, 8), 256, 0, stream>>>(cond, wT1, np_b1, h1);
    k_conv3m<256, 256, true ><<<dim3(50, 8), 256, 0, stream>>>(h1, wT2, np_b2, h2);
    k_conv3m<128, 128, false><<<dim3(50, 8), 256, 0, stream>>>(cond, wTs, ss_b1, g);
    k_np_part<<<dim3(4, 4, 8), 256, 0, stream>>>(h2, np_w3, part_np);
    k_ss_part<<<dim3(4, 2, 8), 256, 0, stream>>>(g, ss_w2, part_ss);
    k_finalize<<<25, 256, 0, stream>>>(part_np, part_ss, np_b3, ss_b2, nt_w, fb_w,
                                       g_all, h_all, attack, inten);
    k_filter<<<dim3(750, 8), 256, 0, stream>>>(wn, g_all, filt);
    k_out<<<dim3(750, 8), 256, 0, stream>>>(filt, h_all, attack, inten, out);
}

// Round 8
// 192.308 us; speedup vs baseline: 2.3999x; 1.1799x over previous
//
#include <hip/hip_runtime.h>
#include <math.h>

static constexpr int B  = 8;
static constexpr int T  = 800;
static constexpr int L  = 192000;
static constexpr int NB = 24;
static constexpr float SCALE = 800.0f / 192000.0f;  // T/L

typedef __bf16 bf8 __attribute__((ext_vector_type(8)));
typedef float  f4  __attribute__((ext_vector_type(4)));

__device__ __forceinline__ float sigf(float x) { return 1.0f / (1.0f + __expf(-x)); }
__device__ __forceinline__ float leaky(float x) { return x >= 0.0f ? x : 0.1f * x; }
__device__ __forceinline__ unsigned short f2bf(float f) {
    unsigned u = __float_as_uint(f);
    u = u + 0x7FFFu + ((u >> 16) & 1u);
    return (unsigned short)(u >> 16);
}
__device__ __forceinline__ float bflo(unsigned u) { return __uint_as_float(u << 16); }
__device__ __forceinline__ float bfhi(unsigned u) { return __uint_as_float(u & 0xffff0000u); }

__device__ __forceinline__ void interp_idx(int l, int& i0, int& i1, float& w) {
    float pos = ((float)l + 0.5f) * SCALE - 0.5f;
    pos = fminf(fmaxf(pos, 0.0f), (float)(T - 1));
    i0 = (int)pos;                 // pos >= 0, trunc == floor
    i1 = min(i0 + 1, T - 1);
    w = pos - (float)i0;
}

// ---- weight transpose+cast: conv weights -> [tap][cout][cin] bf16 ----
__global__ __launch_bounds__(256) void k_twm(const float* __restrict__ w1,
                                             const float* __restrict__ w2,
                                             const float* __restrict__ wss,
                                             unsigned short* __restrict__ wT1,
                                             unsigned short* __restrict__ wT2,
                                             unsigned short* __restrict__ wTs) {
    int idx = blockIdx.x * 256 + threadIdx.x;
    if (idx < 98304) {                        // np_w1 [256][128][3]
        int tap = idx / (256 * 128), r = idx % (256 * 128);
        int cout = r / 128, cin = r % 128;
        wT1[idx] = f2bf(w1[(cout * 128 + cin) * 3 + tap]);
    } else if (idx < 98304 + 196608) {        // np_w2 [256][256][3]
        int j = idx - 98304;
        int tap = j / (256 * 256), r = j % (256 * 256);
        int cout = r / 256, cin = r % 256;
        wT2[j] = f2bf(w2[(cout * 256 + cin) * 3 + tap]);
    } else if (idx < 98304 + 196608 + 49152) {// ss_w1 [128][128][3]
        int j = idx - 294912;
        int tap = j / (128 * 128), r = j % (128 * 128);
        int cout = r / 128, cin = r % 128;
        wTs[j] = f2bf(wss[(cout * 128 + cin) * 3 + tap]);
    }
}

// ---------------- MFMA k=3 conv, pad=1, leaky; out bf16 (np conv1) ----------------
template<int CIN, int COUT, bool INBF>
__global__ __launch_bounds__(256) void k_conv3m(const void* __restrict__ xin,
                                                const unsigned short* __restrict__ wT,
                                                const float* __restrict__ bias,
                                                unsigned short* __restrict__ y) {
    constexpr int CINP = CIN + 8;
    constexpr int MT = COUT / 64;
    __shared__ unsigned short xs[18 * CINP];  // xs[t_local][cin], bf16
    const int b = blockIdx.y;
    const int t0 = blockIdx.x * 16;
    const int tid = threadIdx.x;
    const float* xf = (const float*)xin;
    const unsigned short* xb = (const unsigned short*)xin;
    for (int i = tid; i < 18 * CIN; i += 256) {
        int cin = i / 18, tr = i % 18;
        int t = t0 + tr - 1;
        unsigned short bits = 0;
        if (t >= 0 && t < T) {
            if (INBF) bits = xb[(b * CIN + cin) * T + t];
            else      bits = f2bf(xf[(b * CIN + cin) * T + t]);
        }
        xs[tr * CINP + cin] = bits;
    }
    __syncthreads();
    const int wave = tid >> 6, lane = tid & 63;
    const int coutb = wave * (COUT / 4);
    const int nfr = lane & 15;
    const int ko8 = (lane >> 4) * 8;
    f4 acc[MT] = {};
#pragma unroll
    for (int tap = 0; tap < 3; ++tap) {
        const unsigned short* wp = wT + ((tap * COUT + coutb + nfr) * CIN + ko8);
        const unsigned short* xp = xs + (nfr + tap) * CINP + ko8;
#pragma unroll 2
        for (int kc = 0; kc < CIN; kc += 32) {
            bf8 bv = *reinterpret_cast<const bf8*>(xp + kc);
#pragma unroll
            for (int m = 0; m < MT; ++m) {
                bf8 av = *reinterpret_cast<const bf8*>(wp + m * 16 * CIN + kc);
                acc[m] = __builtin_amdgcn_mfma_f32_16x16x32_bf16(av, bv, acc[m], 0, 0, 0);
            }
        }
    }
    const int rb = (lane >> 4) * 4;
    const int tcol = lane & 15;
#pragma unroll
    for (int m = 0; m < MT; ++m) {
#pragma unroll
        for (int r = 0; r < 4; ++r) {
            int cout = coutb + m * 16 + rb + r;
            float v = leaky(acc[m][r] + bias[cout]);
            y[(b * COUT + cout) * T + t0 + tcol] = f2bf(v);
        }
    }
}

// ------- np conv2 (256->256 MFMA) + head (256->27, f32 VALU) + h_all, fused -------
__global__ __launch_bounds__(256) void k_np_fused(const unsigned short* __restrict__ h1,
                                                  const unsigned short* __restrict__ wT,
                                                  const float* __restrict__ bias,
                                                  const float* __restrict__ w3,
                                                  const float* __restrict__ b3,
                                                  const float* __restrict__ fbw,
                                                  float* __restrict__ h_all,
                                                  float* __restrict__ attack,
                                                  float* __restrict__ inten) {
    constexpr int CIN = 256, COUT = 256, CINP = 264;
    __shared__ unsigned short xs[18 * CINP];
    __shared__ unsigned short h2s[16 * CINP];   // h2s[t][cout]
    __shared__ float bnd[16][25];               // sigmoid band amps [t][c]
    const int b = blockIdx.y;
    const int t0 = blockIdx.x * 16;
    const int tid = threadIdx.x;
    for (int i = tid; i < 18 * CIN; i += 256) {
        int cin = i / 18, tr = i % 18;
        int t = t0 + tr - 1;
        xs[tr * CINP + cin] = (t >= 0 && t < T) ? h1[(b * CIN + cin) * T + t]
                                                : (unsigned short)0;
    }
    __syncthreads();
    const int wave = tid >> 6, lane = tid & 63;
    const int coutb = wave * 64;
    const int nfr = lane & 15;
    const int ko8 = (lane >> 4) * 8;
    f4 acc[4] = {};
#pragma unroll
    for (int tap = 0; tap < 3; ++tap) {
        const unsigned short* wp = wT + ((tap * COUT + coutb + nfr) * CIN + ko8);
        const unsigned short* xp = xs + (nfr + tap) * CINP + ko8;
#pragma unroll 2
        for (int kc = 0; kc < CIN; kc += 32) {
            bf8 bv = *reinterpret_cast<const bf8*>(xp + kc);
#pragma unroll
            for (int m = 0; m < 4; ++m) {
                bf8 av = *reinterpret_cast<const bf8*>(wp + m * 16 * CIN + kc);
                acc[m] = __builtin_amdgcn_mfma_f32_16x16x32_bf16(av, bv, acc[m], 0, 0, 0);
            }
        }
    }
    const int rb = (lane >> 4) * 4;
    const int tcol = lane & 15;
#pragma unroll
    for (int m = 0; m < 4; ++m) {
        ushort4 pk;
        pk.x = f2bf(leaky(acc[m][0] + bias[coutb + m * 16 + rb + 0]));
        pk.y = f2bf(leaky(acc[m][1] + bias[coutb + m * 16 + rb + 1]));
        pk.z = f2bf(leaky(acc[m][2] + bias[coutb + m * 16 + rb + 2]));
        pk.w = f2bf(leaky(acc[m][3] + bias[coutb + m * 16 + rb + 3]));
        *reinterpret_cast<ushort4*>(&h2s[tcol * CINP + coutb + m * 16 + rb]) = pk;
    }
    __syncthreads();
    // head in f32; work item i -> (c = i/16, t = i&15); 432 items
    for (int i = tid; i < 27 * 16; i += 256) {
        int c = i >> 4, t = i & 15;
        float s = b3[c];
        const unsigned short* hp = &h2s[t * CINP];
        const float* wp3 = w3 + c * 256;
#pragma unroll 4
        for (int kk = 0; kk < 256; kk += 8) {
            uint4 u = *reinterpret_cast<const uint4*>(hp + kk);
            float4 wa = *reinterpret_cast<const float4*>(wp3 + kk);
            float4 wb = *reinterpret_cast<const float4*>(wp3 + kk + 4);
            s += bflo(u.x) * wa.x + bfhi(u.x) * wa.y
               + bflo(u.y) * wa.z + bfhi(u.y) * wa.w
               + bflo(u.z) * wb.x + bfhi(u.z) * wb.y
               + bflo(u.w) * wb.z + bfhi(u.w) * wb.w;
        }
        if (c < 24) bnd[t][c] = sigf(s);
        else if (c == 24) attack[b * T + t0 + t] = sigf(s) * 10.0f;
        else if (c == 26) inten[b * T + t0 + t] = sigf(s);
    }
    __syncthreads();
    // h_all[b][k][t] = sum_c bnd[t][c] * fbw[c][k]
    for (int i = tid; i < 31 * 16; i += 256) {
        int k = i >> 4, t = i & 15;
        float s = 0.0f;
#pragma unroll
        for (int c = 0; c < NB; ++c) s += bnd[t][c] * fbw[c * 31 + k];
        h_all[(b * 31 + k) * T + t0 + t] = s;
    }
}

// ------- ss conv (128->128 MFMA) + head (128->4) + softmax + g_all, fused -------
__global__ __launch_bounds__(256) void k_ss_fused(const float* __restrict__ cond,
                                                  const unsigned short* __restrict__ wT,
                                                  const float* __restrict__ bias,
                                                  const float* __restrict__ w2,
                                                  const float* __restrict__ b2,
                                                  const float* __restrict__ ntf,
                                                  float* __restrict__ g_all) {
    constexpr int CIN = 128, COUT = 128, CINP = 136;
    __shared__ unsigned short xs[18 * CINP];
    __shared__ unsigned short gs[16 * CINP];    // g[t][cout]
    __shared__ float sv[16][5];
    __shared__ float nws[16][5];
    const int b = blockIdx.y;
    const int t0 = blockIdx.x * 16;
    const int tid = threadIdx.x;
    for (int i = tid; i < 18 * CIN; i += 256) {
        int cin = i / 18, tr = i % 18;
        int t = t0 + tr - 1;
        xs[tr * CINP + cin] = (t >= 0 && t < T) ? f2bf(cond[(b * CIN + cin) * T + t])
                                                : (unsigned short)0;
    }
    __syncthreads();
    const int wave = tid >> 6, lane = tid & 63;
    const int coutb = wave * 32;
    const int nfr = lane & 15;
    const int ko8 = (lane >> 4) * 8;
    f4 acc[2] = {};
#pragma unroll
    for (int tap = 0; tap < 3; ++tap) {
        const unsigned short* wp = wT + ((tap * COUT + coutb + nfr) * CIN + ko8);
        const unsigned short* xp = xs + (nfr + tap) * CINP + ko8;
#pragma unroll
        for (int kc = 0; kc < CIN; kc += 32) {
            bf8 bv = *reinterpret_cast<const bf8*>(xp + kc);
#pragma unroll
            for (int m = 0; m < 2; ++m) {
                bf8 av = *reinterpret_cast<const bf8*>(wp + m * 16 * CIN + kc);
                acc[m] = __builtin_amdgcn_mfma_f32_16x16x32_bf16(av, bv, acc[m], 0, 0, 0);
            }
        }
    }
    const int rb = (lane >> 4) * 4;
    const int tcol = lane & 15;
#pragma unroll
    for (int m = 0; m < 2; ++m) {
        ushort4 pk;
        pk.x = f2bf(leaky(acc[m][0] + bias[coutb + m * 16 + rb + 0]));
        pk.y = f2bf(leaky(acc[m][1] + bias[coutb + m * 16 + rb + 1]));
        pk.z = f2bf(leaky(acc[m][2] + bias[coutb + m * 16 + rb + 2]));
        pk.w = f2bf(leaky(acc[m][3] + bias[coutb + m * 16 + rb + 3]));
        *reinterpret_cast<ushort4*>(&gs[tcol * CINP + coutb + m * 16 + rb]) = pk;
    }
    __syncthreads();
    if (tid < 64) {
        int c = tid & 3, tl = tid >> 2;
        float s = b2[c];
#pragma unroll
        for (int kk = 0; kk < 128; kk += 8) {
            uint4 u = *reinterpret_cast<const uint4*>(&gs[tl * CINP + kk]);
            float4 wa = *reinterpret_cast<const float4*>(&w2[c * 128 + kk]);
            float4 wb = *reinterpret_cast<const float4*>(&w2[c * 128 + kk + 4]);
            s += bflo(u.x) * wa.x + bfhi(u.x) * wa.y
               + bflo(u.y) * wa.z + bfhi(u.y) * wa.w
               + bflo(u.z) * wb.x + bfhi(u.z) * wb.y
               + bflo(u.w) * wb.z + bfhi(u.w) * wb.w;
        }
        sv[tl][c] = s;
    }
    __syncthreads();
    if (tid < 16) {
        float a0 = sv[tid][0], a1 = sv[tid][1], a2 = sv[tid][2], a3 = sv[tid][3];
        float m = fmaxf(fmaxf(a0, a1), fmaxf(a2, a3));
        float e0 = __expf(a0 - m), e1 = __expf(a1 - m), e2 = __expf(a2 - m), e3 = __expf(a3 - m);
        float inv = 1.0f / (e0 + e1 + e2 + e3);
        nws[tid][0] = e0 * inv; nws[tid][1] = e1 * inv;
        nws[tid][2] = e2 * inv; nws[tid][3] = e3 * inv;
    }
    __syncthreads();
    // g_all[b][k][t] = sum_c nws[t][c] * ntf[c][k]
    for (int i = tid; i < 63 * 16; i += 256) {
        int k = i >> 4, t = i & 15;
        float s = nws[t][0] * ntf[k] + nws[t][1] * ntf[63 + k]
                + nws[t][2] * ntf[126 + k] + nws[t][3] * ntf[189 + k];
        g_all[(b * 63 + k) * T + t0 + t] = s;
    }
}

// ---------------- fused sample-rate: 63-tap mix + 31-tap mix + gate + outputs ----------------
__device__ __forceinline__ float interp_T(const float* __restrict__ a, int b, int p) {
    int i0, i1; float w;
    interp_idx(p, i0, i1, w);
    return a[b * T + i0] * (1.0f - w) + a[b * T + i1] * w;
}

__device__ __forceinline__ int refl(int p) {
    return p < 0 ? -p : (p >= L ? 2 * L - 2 - p : p);
}

__global__ __launch_bounds__(256) void k_sr(const float* __restrict__ wn,
                                            const float* __restrict__ g_all,
                                            const float* __restrict__ h_all,
                                            const float* __restrict__ attack,
                                            const float* __restrict__ inten,
                                            float* __restrict__ out) {
    __shared__ float wns[348];   // wn[l0-46 .. l0+301]
    __shared__ float gl[4][63];
    __shared__ float hl[4][31];
    __shared__ float flt[286];   // filtered[l0-15 .. l0+270]
    __shared__ float ipl[261];   // intensity_up(l0-3+i)
    __shared__ float gp[260];    // gate_pre(l0-2+i) (reflected)
    const int b = blockIdx.y;
    const int l0 = blockIdx.x * 256;
    const int tid = threadIdx.x;
    for (int i = tid; i < 348; i += 256) {
        int p = l0 - 46 + i;
        wns[i] = (p >= 0 && p < L) ? wn[b * L + p] : 0.0f;
    }
    int fg0, fgu; float wgu;
    interp_idx(l0 - 15, fg0, fgu, wgu);   // frame base for all staged filters
    for (int i = tid; i < 376; i += 256) { // gl (252) + hl (124) in one strided loop
        if (i < 252) {
            int j = i / 63, k = i % 63;
            int f = min(fg0 + j, T - 1);
            gl[j][k] = g_all[(b * 63 + k) * T + f];
        } else {
            int j2 = (i - 252) / 31, k2 = (i - 252) % 31;
            int f = min(fg0 + j2, T - 1);
            hl[j2][k2] = h_all[(b * 31 + k2) * T + f];
        }
    }
    for (int i = tid; i < 261; i += 256)
        ipl[i] = interp_T(inten, b, l0 - 3 + i);
    __syncthreads();
    // gate precompute
    for (int i = tid; i < 260; i += 256) {
        int p = l0 - 2 + i;
        int pr = refl(p);
        float cur = ipl[pr - l0 + 3];
        float prev = (pr == 0) ? cur : ipl[pr - 1 - l0 + 3];
        float diff = cur - prev;
        float ar = interp_T(attack, b, pr);
        float enh = fminf(fmaxf(cur + (diff > 0.1f ? ar * 0.3f : 0.0f), 0.0f), 1.0f);
        gp[i] = (diff > 0.0f) ? enh : cur;
    }
    // filtered = 63-tap frame-lerped conv of white noise.
    // CRITICAL: the reference zero-pads the INTERMEDIATE `filtered` signal for
    // the 31-tap conv (pad=15) — so flt must be EXACTLY 0 outside [0,L), not
    // the FIR of zero-padded wn. (Round-6/7 bug: absmax 0.1875 at row edges.)
    for (int i = tid; i < 286; i += 256) {
        int p = l0 - 15 + i;
        float v = 0.0f;
        if (p >= 0 && p < L) {
            int i0, i1; float w;
            interp_idx(p, i0, i1, w);
            int d0 = min(max(i0 - fg0, 0), 3);
            int d1 = min(max(i1 - fg0, 0), 3);
            float a0 = 0.0f, a1 = 0.0f;
#pragma unroll
            for (int k = 0; k < 63; ++k) {
                float xk = wns[i + k];
                a0 += xk * gl[d0][k];
                a1 += xk * gl[d1][k];
            }
            v = (1.0f - w) * a0 + w * a1;
        }
        flt[i] = v;
    }
    __syncthreads();
    const int l = l0 + tid;
    int i0, i1; float w;
    interp_idx(l, i0, i1, w);
    int d0 = min(max(i0 - fg0, 0), 3);
    int d1 = min(max(i1 - fg0, 0), 3);
    float a0 = 0.0f, a1 = 0.0f;
#pragma unroll
    for (int k = 0; k < 31; ++k) {
        float xk = flt[tid + k];
        a0 += xk * hl[d0][k];
        a1 += xk * hl[d1][k];
    }
    float shaped = (1.0f - w) * a0 + w * a1;
    float g5 = (gp[tid] + gp[tid + 1] + gp[tid + 2] + gp[tid + 3] + gp[tid + 4]) * 0.2f;
    out[b * L + l] = shaped * g5;
    out[B * L + b * L + l] = g5;
}

extern "C" void kernel_launch(void* const* d_in, const int* in_sizes, int n_in,
                              void* d_out, int out_size, void* d_ws, size_t ws_size,
                              hipStream_t stream) {
    const float* cond  = (const float*)d_in[0];
    const float* wn    = (const float*)d_in[1];
    const float* np_w1 = (const float*)d_in[2];
    const float* np_b1 = (const float*)d_in[3];
    const float* np_w2 = (const float*)d_in[4];
    const float* np_b2 = (const float*)d_in[5];
    const float* np_w3 = (const float*)d_in[6];
    const float* np_b3 = (const float*)d_in[7];
    const float* ss_w1 = (const float*)d_in[8];
    const float* ss_b1 = (const float*)d_in[9];
    const float* ss_w2 = (const float*)d_in[10];
    const float* ss_b2 = (const float*)d_in[11];
    const float* fb_w  = (const float*)d_in[12];
    const float* nt_w  = (const float*)d_in[13];

    char* p = (char*)d_ws;
    unsigned short* wT1 = (unsigned short*)p; p += 196608;   // [3][256][128] bf16
    unsigned short* wT2 = (unsigned short*)p; p += 393216;   // [3][256][256] bf16
    unsigned short* wTs = (unsigned short*)p; p += 98304;    // [3][128][128] bf16
    unsigned short* h1  = (unsigned short*)p; p += 3276800;  // [8][256][800] bf16
    float* attack = (float*)p; p += 25600;                   // [8][800]
    float* inten  = (float*)p; p += 25600;                   // [8][800]
    float* g_all  = (float*)p; p += 1612800;                 // [8][63][800]
    float* h_all  = (float*)p; p += 793600;                  // [8][31][800]
    float* out = (float*)d_out;

    k_twm<<<1344, 256, 0, stream>>>(np_w1, np_w2, ss_w1, wT1, wT2, wTs);
    k_conv3m<128, 256, false><<<dim3(50, 8), 256, 0, stream>>>(cond, wT1, np_b1, h1);
    k_ss_fused<<<dim3(50, 8), 256, 0, stream>>>(cond, wTs, ss_b1, ss_w2, ss_b2, nt_w, g_all);
    k_np_fused<<<dim3(50, 8), 256, 0, stream>>>(h1, wT2, np_b2, np_w3, np_b3, fb_w,
                                                h_all, attack, inten);
    k_sr<<<dim3(750, 8), 256, 0, stream>>>(wn, g_all, h_all, attack, inten, out);
}

// Round 9
// 176.364 us; speedup vs baseline: 2.6169x; 1.0904x over previous
//
#include <hip/hip_runtime.h>
#include <math.h>

static constexpr int B  = 8;
static constexpr int T  = 800;
static constexpr int L  = 192000;
static constexpr int NB = 24;
static constexpr float SCALE = 800.0f / 192000.0f;  // T/L

typedef __bf16 bf8 __attribute__((ext_vector_type(8)));
typedef float  f4  __attribute__((ext_vector_type(4)));

__device__ __forceinline__ float sigf(float x) { return 1.0f / (1.0f + __expf(-x)); }
__device__ __forceinline__ float leaky(float x) { return x >= 0.0f ? x : 0.1f * x; }
__device__ __forceinline__ unsigned short f2bf(float f) {
    unsigned u = __float_as_uint(f);
    u = u + 0x7FFFu + ((u >> 16) & 1u);
    return (unsigned short)(u >> 16);
}
__device__ __forceinline__ float bflo(unsigned u) { return __uint_as_float(u << 16); }
__device__ __forceinline__ float bfhi(unsigned u) { return __uint_as_float(u & 0xffff0000u); }

__device__ __forceinline__ void interp_idx(int l, int& i0, int& i1, float& w) {
    float pos = ((float)l + 0.5f) * SCALE - 0.5f;
    pos = fminf(fmaxf(pos, 0.0f), (float)(T - 1));
    i0 = (int)pos;
    i1 = min(i0 + 1, T - 1);
    w = pos - (float)i0;
}

// ---- weight transpose+cast: conv weights -> [tap][cout][cin] bf16 ----
__global__ __launch_bounds__(256) void k_twm(const float* __restrict__ w1,
                                             const float* __restrict__ w2,
                                             const float* __restrict__ wss,
                                             unsigned short* __restrict__ wT1,
                                             unsigned short* __restrict__ wT2,
                                             unsigned short* __restrict__ wTs) {
    int idx = blockIdx.x * 256 + threadIdx.x;
    if (idx < 98304) {                        // np_w1 [256][128][3]
        int tap = idx / (256 * 128), r = idx % (256 * 128);
        int cout = r / 128, cin = r % 128;
        wT1[idx] = f2bf(w1[(cout * 128 + cin) * 3 + tap]);
    } else if (idx < 98304 + 196608) {        // np_w2 [256][256][3]
        int j = idx - 98304;
        int tap = j / (256 * 256), r = j % (256 * 256);
        int cout = r / 256, cin = r % 256;
        wT2[j] = f2bf(w2[(cout * 256 + cin) * 3 + tap]);
    } else if (idx < 98304 + 196608 + 49152) {// ss_w1 [128][128][3]
        int j = idx - 294912;
        int tap = j / (128 * 128), r = j % (128 * 128);
        int cout = r / 128, cin = r % 128;
        wTs[j] = f2bf(wss[(cout * 128 + cin) * 3 + tap]);
    }
}

// ---- mega: z=0 -> np chain (conv1+conv2+head+h_all); z=1 -> ss chain ----
union SMem {
    struct {
        unsigned short xs[20 * 136];     // cond cols t0-2..t0+17
        unsigned short h1s[18 * 264];    // h1 cols t0-1..t0+16 (zeroed outside [0,T))
        unsigned short h2s[16 * 264];    // h2 cols t0..t0+15
        float bnd[16][25];
    } np;
    struct {
        unsigned short xs[18 * 136];
        unsigned short gs[16 * 136];
        float sv[16][5];
        float nws[16][5];
    } ss;
};

__global__ __launch_bounds__(256) void k_mega(const float* __restrict__ cond,
                                              const unsigned short* __restrict__ wT1,
                                              const float* __restrict__ b1,
                                              const unsigned short* __restrict__ wT2,
                                              const float* __restrict__ b2np,
                                              const float* __restrict__ w3,
                                              const float* __restrict__ b3,
                                              const float* __restrict__ fbw,
                                              const unsigned short* __restrict__ wTs,
                                              const float* __restrict__ bss,
                                              const float* __restrict__ w2ss,
                                              const float* __restrict__ b2ss,
                                              const float* __restrict__ ntf,
                                              float* __restrict__ h_all,
                                              float* __restrict__ g_all,
                                              float* __restrict__ attack,
                                              float* __restrict__ inten) {
    __shared__ SMem sm;
    const int b = blockIdx.y;
    const int t0 = blockIdx.x * 16;
    const int tid = threadIdx.x;
    const int wave = tid >> 6, lane = tid & 63;
    const int nfr = lane & 15;
    const int ko8 = (lane >> 4) * 8;
    const int rb = (lane >> 4) * 4;
    const int tcol = lane & 15;

    if (blockIdx.z == 0) {
        // ================= NP chain =================
        // stage cond cols t0-2 .. t0+17 (20 cols), bf16
        for (int i = tid; i < 20 * 128; i += 256) {
            int cin = i / 20, j = i % 20;
            int t = t0 - 2 + j;
            sm.np.xs[j * 136 + cin] = (t >= 0 && t < T) ? f2bf(cond[(b * 128 + cin) * T + t])
                                                        : (unsigned short)0;
        }
        __syncthreads();
        const int coutb = wave * 64;
        // conv1: 2 n-tiles cover output cols t0-1 .. t0+30 (first 18 kept)
        f4 a1[2][4] = {};
#pragma unroll
        for (int tap = 0; tap < 3; ++tap) {
#pragma unroll
            for (int kc = 0; kc < 128; kc += 32) {
                bf8 bv0 = *reinterpret_cast<const bf8*>(&sm.np.xs[(nfr + tap) * 136 + kc + ko8]);
                bf8 bv1 = *reinterpret_cast<const bf8*>(&sm.np.xs[(nfr + 16 + tap) * 136 + kc + ko8]);
#pragma unroll
                for (int m = 0; m < 4; ++m) {
                    bf8 av = *reinterpret_cast<const bf8*>(
                        wT1 + ((tap * 256 + coutb + m * 16 + nfr) * 128 + kc + ko8));
                    a1[0][m] = __builtin_amdgcn_mfma_f32_16x16x32_bf16(av, bv0, a1[0][m], 0, 0, 0);
                    a1[1][m] = __builtin_amdgcn_mfma_f32_16x16x32_bf16(av, bv1, a1[1][m], 0, 0, 0);
                }
            }
        }
        // h1 -> LDS; cols outside [0,T) are EXACT zeros (conv2's zero padding)
#pragma unroll
        for (int nt = 0; nt < 2; ++nt) {
            int lcol = nt * 16 + tcol;
            if (lcol < 18) {
                int gcol = t0 - 1 + lcol;
                bool ok = (gcol >= 0 && gcol < T);
#pragma unroll
                for (int m = 0; m < 4; ++m) {
                    ushort4 pk;
                    if (ok) {
                        pk.x = f2bf(leaky(a1[nt][m][0] + b1[coutb + m * 16 + rb + 0]));
                        pk.y = f2bf(leaky(a1[nt][m][1] + b1[coutb + m * 16 + rb + 1]));
                        pk.z = f2bf(leaky(a1[nt][m][2] + b1[coutb + m * 16 + rb + 2]));
                        pk.w = f2bf(leaky(a1[nt][m][3] + b1[coutb + m * 16 + rb + 3]));
                    } else {
                        pk.x = pk.y = pk.z = pk.w = 0;
                    }
                    *reinterpret_cast<ushort4*>(&sm.np.h1s[lcol * 264 + coutb + m * 16 + rb]) = pk;
                }
            }
        }
        __syncthreads();
        // conv2: 256->256, reading h1s (row j = col t0-1+j)
        f4 a2[4] = {};
#pragma unroll
        for (int tap = 0; tap < 3; ++tap) {
#pragma unroll 2
            for (int kc = 0; kc < 256; kc += 32) {
                bf8 bv = *reinterpret_cast<const bf8*>(&sm.np.h1s[(nfr + tap) * 264 + kc + ko8]);
#pragma unroll
                for (int m = 0; m < 4; ++m) {
                    bf8 av = *reinterpret_cast<const bf8*>(
                        wT2 + ((tap * 256 + coutb + m * 16 + nfr) * 256 + kc + ko8));
                    a2[m] = __builtin_amdgcn_mfma_f32_16x16x32_bf16(av, bv, a2[m], 0, 0, 0);
                }
            }
        }
#pragma unroll
        for (int m = 0; m < 4; ++m) {
            ushort4 pk;
            pk.x = f2bf(leaky(a2[m][0] + b2np[coutb + m * 16 + rb + 0]));
            pk.y = f2bf(leaky(a2[m][1] + b2np[coutb + m * 16 + rb + 1]));
            pk.z = f2bf(leaky(a2[m][2] + b2np[coutb + m * 16 + rb + 2]));
            pk.w = f2bf(leaky(a2[m][3] + b2np[coutb + m * 16 + rb + 3]));
            *reinterpret_cast<ushort4*>(&sm.np.h2s[tcol * 264 + coutb + m * 16 + rb]) = pk;
        }
        __syncthreads();
        // head in f32; item i -> (c = i/16, t = i&15)
        for (int i = tid; i < 27 * 16; i += 256) {
            int c = i >> 4, t = i & 15;
            float s = b3[c];
            const unsigned short* hp = &sm.np.h2s[t * 264];
            const float* wp3 = w3 + c * 256;
#pragma unroll 4
            for (int kk = 0; kk < 256; kk += 8) {
                uint4 u = *reinterpret_cast<const uint4*>(hp + kk);
                float4 wa = *reinterpret_cast<const float4*>(wp3 + kk);
                float4 wb = *reinterpret_cast<const float4*>(wp3 + kk + 4);
                s += bflo(u.x) * wa.x + bfhi(u.x) * wa.y
                   + bflo(u.y) * wa.z + bfhi(u.y) * wa.w
                   + bflo(u.z) * wb.x + bfhi(u.z) * wb.y
                   + bflo(u.w) * wb.z + bfhi(u.w) * wb.w;
            }
            if (c < 24) sm.np.bnd[t][c] = sigf(s);
            else if (c == 24) attack[b * T + t0 + t] = sigf(s) * 10.0f;
            else if (c == 26) inten[b * T + t0 + t] = sigf(s);
        }
        __syncthreads();
        // h_all[b][k][t] = sum_c bnd[t][c] * fbw[c][k]
        for (int i = tid; i < 31 * 16; i += 256) {
            int k = i >> 4, t = i & 15;
            float s = 0.0f;
#pragma unroll
            for (int c = 0; c < NB; ++c) s += sm.np.bnd[t][c] * fbw[c * 31 + k];
            h_all[(b * 31 + k) * T + t0 + t] = s;
        }
    } else {
        // ================= SS chain =================
        for (int i = tid; i < 18 * 128; i += 256) {
            int cin = i / 18, tr = i % 18;
            int t = t0 + tr - 1;
            sm.ss.xs[tr * 136 + cin] = (t >= 0 && t < T) ? f2bf(cond[(b * 128 + cin) * T + t])
                                                         : (unsigned short)0;
        }
        __syncthreads();
        const int coutb = wave * 32;
        f4 acc[2] = {};
#pragma unroll
        for (int tap = 0; tap < 3; ++tap) {
#pragma unroll
            for (int kc = 0; kc < 128; kc += 32) {
                bf8 bv = *reinterpret_cast<const bf8*>(&sm.ss.xs[(nfr + tap) * 136 + kc + ko8]);
#pragma unroll
                for (int m = 0; m < 2; ++m) {
                    bf8 av = *reinterpret_cast<const bf8*>(
                        wTs + ((tap * 128 + coutb + m * 16 + nfr) * 128 + kc + ko8));
                    acc[m] = __builtin_amdgcn_mfma_f32_16x16x32_bf16(av, bv, acc[m], 0, 0, 0);
                }
            }
        }
#pragma unroll
        for (int m = 0; m < 2; ++m) {
            ushort4 pk;
            pk.x = f2bf(leaky(acc[m][0] + bss[coutb + m * 16 + rb + 0]));
            pk.y = f2bf(leaky(acc[m][1] + bss[coutb + m * 16 + rb + 1]));
            pk.z = f2bf(leaky(acc[m][2] + bss[coutb + m * 16 + rb + 2]));
            pk.w = f2bf(leaky(acc[m][3] + bss[coutb + m * 16 + rb + 3]));
            *reinterpret_cast<ushort4*>(&sm.ss.gs[tcol * 136 + coutb + m * 16 + rb]) = pk;
        }
        __syncthreads();
        if (tid < 64) {
            int c = tid & 3, tl = tid >> 2;
            float s = b2ss[c];
#pragma unroll
            for (int kk = 0; kk < 128; kk += 8) {
                uint4 u = *reinterpret_cast<const uint4*>(&sm.ss.gs[tl * 136 + kk]);
                float4 wa = *reinterpret_cast<const float4*>(&w2ss[c * 128 + kk]);
                float4 wb = *reinterpret_cast<const float4*>(&w2ss[c * 128 + kk + 4]);
                s += bflo(u.x) * wa.x + bfhi(u.x) * wa.y
                   + bflo(u.y) * wa.z + bfhi(u.y) * wa.w
                   + bflo(u.z) * wb.x + bfhi(u.z) * wb.y
                   + bflo(u.w) * wb.z + bfhi(u.w) * wb.w;
            }
            sm.ss.sv[tl][c] = s;
        }
        __syncthreads();
        if (tid < 16) {
            float a0 = sm.ss.sv[tid][0], a1v = sm.ss.sv[tid][1];
            float a2v = sm.ss.sv[tid][2], a3v = sm.ss.sv[tid][3];
            float m = fmaxf(fmaxf(a0, a1v), fmaxf(a2v, a3v));
            float e0 = __expf(a0 - m), e1 = __expf(a1v - m);
            float e2 = __expf(a2v - m), e3 = __expf(a3v - m);
            float inv = 1.0f / (e0 + e1 + e2 + e3);
            sm.ss.nws[tid][0] = e0 * inv; sm.ss.nws[tid][1] = e1 * inv;
            sm.ss.nws[tid][2] = e2 * inv; sm.ss.nws[tid][3] = e3 * inv;
        }
        __syncthreads();
        for (int i = tid; i < 63 * 16; i += 256) {
            int k = i >> 4, t = i & 15;
            float s = sm.ss.nws[t][0] * ntf[k] + sm.ss.nws[t][1] * ntf[63 + k]
                    + sm.ss.nws[t][2] * ntf[126 + k] + sm.ss.nws[t][3] * ntf[189 + k];
            g_all[(b * 63 + k) * T + t0 + t] = s;
        }
    }
}

// ---------------- fused sample-rate (unchanged from passing round 8) ----------------
__device__ __forceinline__ float interp_T(const float* __restrict__ a, int b, int p) {
    int i0, i1; float w;
    interp_idx(p, i0, i1, w);
    return a[b * T + i0] * (1.0f - w) + a[b * T + i1] * w;
}

__device__ __forceinline__ int refl(int p) {
    return p < 0 ? -p : (p >= L ? 2 * L - 2 - p : p);
}

__global__ __launch_bounds__(256) void k_sr(const float* __restrict__ wn,
                                            const float* __restrict__ g_all,
                                            const float* __restrict__ h_all,
                                            const float* __restrict__ attack,
                                            const float* __restrict__ inten,
                                            float* __restrict__ out) {
    __shared__ float wns[348];
    __shared__ float gl[4][63];
    __shared__ float hl[4][31];
    __shared__ float flt[286];
    __shared__ float ipl[261];
    __shared__ float gp[260];
    const int b = blockIdx.y;
    const int l0 = blockIdx.x * 256;
    const int tid = threadIdx.x;
    for (int i = tid; i < 348; i += 256) {
        int p = l0 - 46 + i;
        wns[i] = (p >= 0 && p < L) ? wn[b * L + p] : 0.0f;
    }
    int fg0, fgu; float wgu;
    interp_idx(l0 - 15, fg0, fgu, wgu);
    for (int i = tid; i < 376; i += 256) {
        if (i < 252) {
            int j = i / 63, k = i % 63;
            int f = min(fg0 + j, T - 1);
            gl[j][k] = g_all[(b * 63 + k) * T + f];
        } else {
            int j2 = (i - 252) / 31, k2 = (i - 252) % 31;
            int f = min(fg0 + j2, T - 1);
            hl[j2][k2] = h_all[(b * 31 + k2) * T + f];
        }
    }
    for (int i = tid; i < 261; i += 256)
        ipl[i] = interp_T(inten, b, l0 - 3 + i);
    __syncthreads();
    for (int i = tid; i < 260; i += 256) {
        int p = l0 - 2 + i;
        int pr = refl(p);
        float cur = ipl[pr - l0 + 3];
        float prev = (pr == 0) ? cur : ipl[pr - 1 - l0 + 3];
        float diff = cur - prev;
        float ar = interp_T(attack, b, pr);
        float enh = fminf(fmaxf(cur + (diff > 0.1f ? ar * 0.3f : 0.0f), 0.0f), 1.0f);
        gp[i] = (diff > 0.0f) ? enh : cur;
    }
    // flt must be EXACT zero outside [0,L) (reference zero-pads the
    // intermediate `filtered` for the 31-tap conv) — round-6/7 lesson.
    for (int i = tid; i < 286; i += 256) {
        int p = l0 - 15 + i;
        float v = 0.0f;
        if (p >= 0 && p < L) {
            int i0, i1; float w;
            interp_idx(p, i0, i1, w);
            int d0 = min(max(i0 - fg0, 0), 3);
            int d1 = min(max(i1 - fg0, 0), 3);
            float a0 = 0.0f, a1 = 0.0f;
#pragma unroll
            for (int k = 0; k < 63; ++k) {
                float xk = wns[i + k];
                a0 += xk * gl[d0][k];
                a1 += xk * gl[d1][k];
            }
            v = (1.0f - w) * a0 + w * a1;
        }
        flt[i] = v;
    }
    __syncthreads();
    const int l = l0 + tid;
    int i0, i1; float w;
    interp_idx(l, i0, i1, w);
    int d0 = min(max(i0 - fg0, 0), 3);
    int d1 = min(max(i1 - fg0, 0), 3);
    float a0 = 0.0f, a1 = 0.0f;
#pragma unroll
    for (int k = 0; k < 31; ++k) {
        float xk = flt[tid + k];
        a0 += xk * hl[d0][k];
        a1 += xk * hl[d1][k];
    }
    float shaped = (1.0f - w) * a0 + w * a1;
    float g5 = (gp[tid] + gp[tid + 1] + gp[tid + 2] + gp[tid + 3] + gp[tid + 4]) * 0.2f;
    out[b * L + l] = shaped * g5;
    out[B * L + b * L + l] = g5;
}

extern "C" void kernel_launch(void* const* d_in, const int* in_sizes, int n_in,
                              void* d_out, int out_size, void* d_ws, size_t ws_size,
                              hipStream_t stream) {
    const float* cond  = (const float*)d_in[0];
    const float* wn    = (const float*)d_in[1];
    const float* np_w1 = (const float*)d_in[2];
    const float* np_b1 = (const float*)d_in[3];
    const float* np_w2 = (const float*)d_in[4];
    const float* np_b2 = (const float*)d_in[5];
    const float* np_w3 = (const float*)d_in[6];
    const float* np_b3 = (const float*)d_in[7];
    const float* ss_w1 = (const float*)d_in[8];
    const float* ss_b1 = (const float*)d_in[9];
    const float* ss_w2 = (const float*)d_in[10];
    const float* ss_b2 = (const float*)d_in[11];
    const float* fb_w  = (const float*)d_in[12];
    const float* nt_w  = (const float*)d_in[13];

    char* p = (char*)d_ws;
    unsigned short* wT1 = (unsigned short*)p; p += 196608;   // [3][256][128] bf16
    unsigned short* wT2 = (unsigned short*)p; p += 393216;   // [3][256][256] bf16
    unsigned short* wTs = (unsigned short*)p; p += 98304;    // [3][128][128] bf16
    float* attack = (float*)p; p += 25600;                   // [8][800]
    float* inten  = (float*)p; p += 25600;                   // [8][800]
    float* g_all  = (float*)p; p += 1612800;                 // [8][63][800]
    float* h_all  = (float*)p; p += 793600;                  // [8][31][800]
    float* out = (float*)d_out;

    k_twm<<<1344, 256, 0, stream>>>(np_w1, np_w2, ss_w1, wT1, wT2, wTs);
    k_mega<<<dim3(50, 8, 2), 256, 0, stream>>>(cond, wT1, np_b1, wT2, np_b2, np_w3, np_b3,
                                               fb_w, wTs, ss_b1, ss_w2, ss_b2, nt_w,
                                               h_all, g_all, attack, inten);
    k_sr<<<dim3(750, 8), 256, 0, stream>>>(wn, g_all, h_all, attack, inten, out);
}

// Round 10
// 168.508 us; speedup vs baseline: 2.7389x; 1.0466x over previous
//
#include <hip/hip_runtime.h>
#include <math.h>

static constexpr int B  = 8;
static constexpr int T  = 800;
static constexpr int L  = 192000;
static constexpr int NB = 24;
static constexpr float SCALE = 800.0f / 192000.0f;  // T/L

typedef __bf16 bf8 __attribute__((ext_vector_type(8)));
typedef float  f4  __attribute__((ext_vector_type(4)));

__device__ __forceinline__ float sigf(float x) { return 1.0f / (1.0f + __expf(-x)); }
__device__ __forceinline__ float leaky(float x) { return x >= 0.0f ? x : 0.1f * x; }
__device__ __forceinline__ unsigned short f2bf(float f) {
    unsigned u = __float_as_uint(f);
    u = u + 0x7FFFu + ((u >> 16) & 1u);
    return (unsigned short)(u >> 16);
}
__device__ __forceinline__ float bflo(unsigned u) { return __uint_as_float(u << 16); }
__device__ __forceinline__ float bfhi(unsigned u) { return __uint_as_float(u & 0xffff0000u); }

__device__ __forceinline__ void interp_idx(int l, int& i0, int& i1, float& w) {
    float pos = ((float)l + 0.5f) * SCALE - 0.5f;
    pos = fminf(fmaxf(pos, 0.0f), (float)(T - 1));
    i0 = (int)pos;
    i1 = min(i0 + 1, T - 1);
    w = pos - (float)i0;
}

// ---- weight transpose+cast: conv weights -> [tap][cout][cin] bf16 ----
__global__ __launch_bounds__(256) void k_twm(const float* __restrict__ w1,
                                             const float* __restrict__ w2,
                                             const float* __restrict__ wss,
                                             unsigned short* __restrict__ wT1,
                                             unsigned short* __restrict__ wT2,
                                             unsigned short* __restrict__ wTs) {
    int idx = blockIdx.x * 256 + threadIdx.x;
    if (idx < 98304) {                        // np_w1 [256][128][3]
        int tap = idx / (256 * 128), r = idx % (256 * 128);
        int cout = r / 128, cin = r % 128;
        wT1[idx] = f2bf(w1[(cout * 128 + cin) * 3 + tap]);
    } else if (idx < 98304 + 196608) {        // np_w2 [256][256][3]
        int j = idx - 98304;
        int tap = j / (256 * 256), r = j % (256 * 256);
        int cout = r / 256, cin = r % 256;
        wT2[j] = f2bf(w2[(cout * 256 + cin) * 3 + tap]);
    } else if (idx < 98304 + 196608 + 49152) {// ss_w1 [128][128][3]
        int j = idx - 294912;
        int tap = j / (128 * 128), r = j % (128 * 128);
        int cout = r / 128, cin = r % 128;
        wTs[j] = f2bf(wss[(cout * 128 + cin) * 3 + tap]);
    }
}

// ---- mega (512 thr / 8 waves): z=0 -> np chain; z=1 -> ss chain ----
union SMem {
    struct {
        unsigned short xs[20 * 136];     // cond cols t0-2..t0+17
        unsigned short h1s[18 * 264];    // h1 cols t0-1..t0+16 (zeroed outside [0,T))
        unsigned short h2s[16 * 264];    // h2 cols t0..t0+15
        float bnd[16][25];
    } np;
    struct {
        unsigned short xs[18 * 136];
        unsigned short gs[16 * 136];
        float sv[16][5];
        float nws[16][5];
    } ss;
};

__global__ __launch_bounds__(512) void k_mega(const float* __restrict__ cond,
                                              const unsigned short* __restrict__ wT1,
                                              const float* __restrict__ b1,
                                              const unsigned short* __restrict__ wT2,
                                              const float* __restrict__ b2np,
                                              const float* __restrict__ w3,
                                              const float* __restrict__ b3,
                                              const float* __restrict__ fbw,
                                              const unsigned short* __restrict__ wTs,
                                              const float* __restrict__ bss,
                                              const float* __restrict__ w2ss,
                                              const float* __restrict__ b2ss,
                                              const float* __restrict__ ntf,
                                              float* __restrict__ h_all,
                                              float* __restrict__ g_all,
                                              float* __restrict__ attack,
                                              float* __restrict__ inten) {
    __shared__ SMem sm;
    const int b = blockIdx.y;
    const int t0 = blockIdx.x * 16;
    const int tid = threadIdx.x;
    const int wave = tid >> 6, lane = tid & 63;   // 8 waves
    const int nfr = lane & 15;
    const int ko8 = (lane >> 4) * 8;
    const int rb = (lane >> 4) * 4;
    const int tcol = lane & 15;

    if (blockIdx.z == 0) {
        // ================= NP chain =================
        for (int i = tid; i < 20 * 128; i += 512) {
            int cin = i / 20, j = i % 20;
            int t = t0 - 2 + j;
            sm.np.xs[j * 136 + cin] = (t >= 0 && t < T) ? f2bf(cond[(b * 128 + cin) * T + t])
                                                        : (unsigned short)0;
        }
        __syncthreads();
        const int coutb = wave * 32;    // 8 waves x 32 couts = 256
        // conv1: 2 n-tiles (cols t0-1..t0+30, first 18 kept), 2 m-tiles/wave
        f4 a1[2][2] = {};
#pragma unroll
        for (int tap = 0; tap < 3; ++tap) {
#pragma unroll
            for (int kc = 0; kc < 128; kc += 32) {
                bf8 bv0 = *reinterpret_cast<const bf8*>(&sm.np.xs[(nfr + tap) * 136 + kc + ko8]);
                bf8 bv1 = *reinterpret_cast<const bf8*>(&sm.np.xs[(nfr + 16 + tap) * 136 + kc + ko8]);
#pragma unroll
                for (int m = 0; m < 2; ++m) {
                    bf8 av = *reinterpret_cast<const bf8*>(
                        wT1 + ((tap * 256 + coutb + m * 16 + nfr) * 128 + kc + ko8));
                    a1[0][m] = __builtin_amdgcn_mfma_f32_16x16x32_bf16(av, bv0, a1[0][m], 0, 0, 0);
                    a1[1][m] = __builtin_amdgcn_mfma_f32_16x16x32_bf16(av, bv1, a1[1][m], 0, 0, 0);
                }
            }
        }
#pragma unroll
        for (int nt = 0; nt < 2; ++nt) {
            int lcol = nt * 16 + tcol;
            if (lcol < 18) {
                int gcol = t0 - 1 + lcol;
                bool ok = (gcol >= 0 && gcol < T);
#pragma unroll
                for (int m = 0; m < 2; ++m) {
                    ushort4 pk;
                    if (ok) {
                        pk.x = f2bf(leaky(a1[nt][m][0] + b1[coutb + m * 16 + rb + 0]));
                        pk.y = f2bf(leaky(a1[nt][m][1] + b1[coutb + m * 16 + rb + 1]));
                        pk.z = f2bf(leaky(a1[nt][m][2] + b1[coutb + m * 16 + rb + 2]));
                        pk.w = f2bf(leaky(a1[nt][m][3] + b1[coutb + m * 16 + rb + 3]));
                    } else {
                        pk.x = pk.y = pk.z = pk.w = 0;
                    }
                    *reinterpret_cast<ushort4*>(&sm.np.h1s[lcol * 264 + coutb + m * 16 + rb]) = pk;
                }
            }
        }
        __syncthreads();
        // conv2: 256->256, 2 m-tiles/wave, fully unrolled (loads issue ahead)
        f4 a2[2] = {};
#pragma unroll
        for (int tap = 0; tap < 3; ++tap) {
#pragma unroll
            for (int kc = 0; kc < 256; kc += 32) {
                bf8 bv = *reinterpret_cast<const bf8*>(&sm.np.h1s[(nfr + tap) * 264 + kc + ko8]);
#pragma unroll
                for (int m = 0; m < 2; ++m) {
                    bf8 av = *reinterpret_cast<const bf8*>(
                        wT2 + ((tap * 256 + coutb + m * 16 + nfr) * 256 + kc + ko8));
                    a2[m] = __builtin_amdgcn_mfma_f32_16x16x32_bf16(av, bv, a2[m], 0, 0, 0);
                }
            }
        }
#pragma unroll
        for (int m = 0; m < 2; ++m) {
            ushort4 pk;
            pk.x = f2bf(leaky(a2[m][0] + b2np[coutb + m * 16 + rb + 0]));
            pk.y = f2bf(leaky(a2[m][1] + b2np[coutb + m * 16 + rb + 1]));
            pk.z = f2bf(leaky(a2[m][2] + b2np[coutb + m * 16 + rb + 2]));
            pk.w = f2bf(leaky(a2[m][3] + b2np[coutb + m * 16 + rb + 3]));
            *reinterpret_cast<ushort4*>(&sm.np.h2s[tcol * 264 + coutb + m * 16 + rb]) = pk;
        }
        __syncthreads();
        // head in f32; item i -> (c = i/16, t = i&15); 432 items over 512 thr
        for (int i = tid; i < 27 * 16; i += 512) {
            int c = i >> 4, t = i & 15;
            float s = b3[c];
            const unsigned short* hp = &sm.np.h2s[t * 264];
            const float* wp3 = w3 + c * 256;
#pragma unroll 4
            for (int kk = 0; kk < 256; kk += 8) {
                uint4 u = *reinterpret_cast<const uint4*>(hp + kk);
                float4 wa = *reinterpret_cast<const float4*>(wp3 + kk);
                float4 wb = *reinterpret_cast<const float4*>(wp3 + kk + 4);
                s += bflo(u.x) * wa.x + bfhi(u.x) * wa.y
                   + bflo(u.y) * wa.z + bfhi(u.y) * wa.w
                   + bflo(u.z) * wb.x + bfhi(u.z) * wb.y
                   + bflo(u.w) * wb.z + bfhi(u.w) * wb.w;
            }
            if (c < 24) sm.np.bnd[t][c] = sigf(s);
            else if (c == 24) attack[b * T + t0 + t] = sigf(s) * 10.0f;
            else if (c == 26) inten[b * T + t0 + t] = sigf(s);
        }
        __syncthreads();
        // h_all[b][k][t] = sum_c bnd[t][c] * fbw[c][k]; 496 items
        for (int i = tid; i < 31 * 16; i += 512) {
            int k = i >> 4, t = i & 15;
            float s = 0.0f;
#pragma unroll
            for (int c = 0; c < NB; ++c) s += sm.np.bnd[t][c] * fbw[c * 31 + k];
            h_all[(b * 31 + k) * T + t0 + t] = s;
        }
    } else {
        // ================= SS chain =================
        for (int i = tid; i < 18 * 128; i += 512) {
            int cin = i / 18, tr = i % 18;
            int t = t0 + tr - 1;
            sm.ss.xs[tr * 136 + cin] = (t >= 0 && t < T) ? f2bf(cond[(b * 128 + cin) * T + t])
                                                         : (unsigned short)0;
        }
        __syncthreads();
        const int coutb = wave * 16;    // 8 waves x 16 couts = 128
        f4 acc = {};
#pragma unroll
        for (int tap = 0; tap < 3; ++tap) {
#pragma unroll
            for (int kc = 0; kc < 128; kc += 32) {
                bf8 bv = *reinterpret_cast<const bf8*>(&sm.ss.xs[(nfr + tap) * 136 + kc + ko8]);
                bf8 av = *reinterpret_cast<const bf8*>(
                    wTs + ((tap * 128 + coutb + nfr) * 128 + kc + ko8));
                acc = __builtin_amdgcn_mfma_f32_16x16x32_bf16(av, bv, acc, 0, 0, 0);
            }
        }
        {
            ushort4 pk;
            pk.x = f2bf(leaky(acc[0] + bss[coutb + rb + 0]));
            pk.y = f2bf(leaky(acc[1] + bss[coutb + rb + 1]));
            pk.z = f2bf(leaky(acc[2] + bss[coutb + rb + 2]));
            pk.w = f2bf(leaky(acc[3] + bss[coutb + rb + 3]));
            *reinterpret_cast<ushort4*>(&sm.ss.gs[tcol * 136 + coutb + rb]) = pk;
        }
        __syncthreads();
        if (tid < 64) {
            int c = tid & 3, tl = tid >> 2;
            float s = b2ss[c];
#pragma unroll
            for (int kk = 0; kk < 128; kk += 8) {
                uint4 u = *reinterpret_cast<const uint4*>(&sm.ss.gs[tl * 136 + kk]);
                float4 wa = *reinterpret_cast<const float4*>(&w2ss[c * 128 + kk]);
                float4 wb = *reinterpret_cast<const float4*>(&w2ss[c * 128 + kk + 4]);
                s += bflo(u.x) * wa.x + bfhi(u.x) * wa.y
                   + bflo(u.y) * wa.z + bfhi(u.y) * wa.w
                   + bflo(u.z) * wb.x + bfhi(u.z) * wb.y
                   + bflo(u.w) * wb.z + bfhi(u.w) * wb.w;
            }
            sm.ss.sv[tl][c] = s;
        }
        __syncthreads();
        if (tid < 16) {
            float a0 = sm.ss.sv[tid][0], a1v = sm.ss.sv[tid][1];
            float a2v = sm.ss.sv[tid][2], a3v = sm.ss.sv[tid][3];
            float m = fmaxf(fmaxf(a0, a1v), fmaxf(a2v, a3v));
            float e0 = __expf(a0 - m), e1 = __expf(a1v - m);
            float e2 = __expf(a2v - m), e3 = __expf(a3v - m);
            float inv = 1.0f / (e0 + e1 + e2 + e3);
            sm.ss.nws[tid][0] = e0 * inv; sm.ss.nws[tid][1] = e1 * inv;
            sm.ss.nws[tid][2] = e2 * inv; sm.ss.nws[tid][3] = e3 * inv;
        }
        __syncthreads();
        for (int i = tid; i < 63 * 16; i += 512) {
            int k = i >> 4, t = i & 15;
            float s = sm.ss.nws[t][0] * ntf[k] + sm.ss.nws[t][1] * ntf[63 + k]
                    + sm.ss.nws[t][2] * ntf[126 + k] + sm.ss.nws[t][3] * ntf[189 + k];
            g_all[(b * 63 + k) * T + t0 + t] = s;
        }
    }
}

// ---------------- fused sample-rate (unchanged, passing numerics) ----------------
__device__ __forceinline__ float interp_T(const float* __restrict__ a, int b, int p) {
    int i0, i1; float w;
    interp_idx(p, i0, i1, w);
    return a[b * T + i0] * (1.0f - w) + a[b * T + i1] * w;
}

__device__ __forceinline__ int refl(int p) {
    return p < 0 ? -p : (p >= L ? 2 * L - 2 - p : p);
}

__global__ __launch_bounds__(256) void k_sr(const float* __restrict__ wn,
                                            const float* __restrict__ g_all,
                                            const float* __restrict__ h_all,
                                            const float* __restrict__ attack,
                                            const float* __restrict__ inten,
                                            float* __restrict__ out) {
    __shared__ float wns[348];
    __shared__ float gl[4][63];
    __shared__ float hl[4][31];
    __shared__ float flt[286];
    __shared__ float ipl[261];
    __shared__ float gp[260];
    const int b = blockIdx.y;
    const int l0 = blockIdx.x * 256;
    const int tid = threadIdx.x;
    for (int i = tid; i < 348; i += 256) {
        int p = l0 - 46 + i;
        wns[i] = (p >= 0 && p < L) ? wn[b * L + p] : 0.0f;
    }
    int fg0, fgu; float wgu;
    interp_idx(l0 - 15, fg0, fgu, wgu);
    for (int i = tid; i < 376; i += 256) {
        if (i < 252) {
            int j = i / 63, k = i % 63;
            int f = min(fg0 + j, T - 1);
            gl[j][k] = g_all[(b * 63 + k) * T + f];
        } else {
            int j2 = (i - 252) / 31, k2 = (i - 252) % 31;
            int f = min(fg0 + j2, T - 1);
            hl[j2][k2] = h_all[(b * 31 + k2) * T + f];
        }
    }
    for (int i = tid; i < 261; i += 256)
        ipl[i] = interp_T(inten, b, l0 - 3 + i);
    __syncthreads();
    for (int i = tid; i < 260; i += 256) {
        int p = l0 - 2 + i;
        int pr = refl(p);
        float cur = ipl[pr - l0 + 3];
        float prev = (pr == 0) ? cur : ipl[pr - 1 - l0 + 3];
        float diff = cur - prev;
        float ar = interp_T(attack, b, pr);
        float enh = fminf(fmaxf(cur + (diff > 0.1f ? ar * 0.3f : 0.0f), 0.0f), 1.0f);
        gp[i] = (diff > 0.0f) ? enh : cur;
    }
    // flt EXACT zero outside [0,L) (reference zero-pads intermediate `filtered`)
    for (int i = tid; i < 286; i += 256) {
        int p = l0 - 15 + i;
        float v = 0.0f;
        if (p >= 0 && p < L) {
            int i0, i1; float w;
            interp_idx(p, i0, i1, w);
            int d0 = min(max(i0 - fg0, 0), 3);
            int d1 = min(max(i1 - fg0, 0), 3);
            float a0 = 0.0f, a1 = 0.0f;
#pragma unroll
            for (int k = 0; k < 63; ++k) {
                float xk = wns[i + k];
                a0 += xk * gl[d0][k];
                a1 += xk * gl[d1][k];
            }
            v = (1.0f - w) * a0 + w * a1;
        }
        flt[i] = v;
    }
    __syncthreads();
    const int l = l0 + tid;
    int i0, i1; float w;
    interp_idx(l, i0, i1, w);
    int d0 = min(max(i0 - fg0, 0), 3);
    int d1 = min(max(i1 - fg0, 0), 3);
    float a0 = 0.0f, a1 = 0.0f;
#pragma unroll
    for (int k = 0; k < 31; ++k) {
        float xk = flt[tid + k];
        a0 += xk * hl[d0][k];
        a1 += xk * hl[d1][k];
    }
    float shaped = (1.0f - w) * a0 + w * a1;
    float g5 = (gp[tid] + gp[tid + 1] + gp[tid + 2] + gp[tid + 3] + gp[tid + 4]) * 0.2f;
    out[b * L + l] = shaped * g5;
    out[B * L + b * L + l] = g5;
}

extern "C" void kernel_launch(void* const* d_in, const int* in_sizes, int n_in,
                              void* d_out, int out_size, void* d_ws, size_t ws_size,
                              hipStream_t stream) {
    const float* cond  = (const float*)d_in[0];
    const float* wn    = (const float*)d_in[1];
    const float* np_w1 = (const float*)d_in[2];
    const float* np_b1 = (const float*)d_in[3];
    const float* np_w2 = (const float*)d_in[4];
    const float* np_b2 = (const float*)d_in[5];
    const float* np_w3 = (const float*)d_in[6];
    const float* np_b3 = (const float*)d_in[7];
    const float* ss_w1 = (const float*)d_in[8];
    const float* ss_b1 = (const float*)d_in[9];
    const float* ss_w2 = (const float*)d_in[10];
    const float* ss_b2 = (const float*)d_in[11];
    const float* fb_w  = (const float*)d_in[12];
    const float* nt_w  = (const float*)d_in[13];

    char* p = (char*)d_ws;
    unsigned short* wT1 = (unsigned short*)p; p += 196608;   // [3][256][128] bf16
    unsigned short* wT2 = (unsigned short*)p; p += 393216;   // [3][256][256] bf16
    unsigned short* wTs = (unsigned short*)p; p += 98304;    // [3][128][128] bf16
    float* attack = (float*)p; p += 25600;                   // [8][800]
    float* inten  = (float*)p; p += 25600;                   // [8][800]
    float* g_all  = (float*)p; p += 1612800;                 // [8][63][800]
    float* h_all  = (float*)p; p += 793600;                  // [8][31][800]
    float* out = (float*)d_out;

    k_twm<<<1344, 256, 0, stream>>>(np_w1, np_w2, ss_w1, wT1, wT2, wTs);
    k_mega<<<dim3(50, 8, 2), 512, 0, stream>>>(cond, wT1, np_b1, wT2, np_b2, np_w3, np_b3,
                                               fb_w, wTs, ss_b1, ss_w2, ss_b2, nt_w,
                                               h_all, g_all, attack, inten);
    k_sr<<<dim3(750, 8), 256, 0, stream>>>(wn, g_all, h_all, attack, inten, out);
}

// Round 11
// 159.032 us; speedup vs baseline: 2.9021x; 1.0596x over previous
//
#include <hip/hip_runtime.h>
#include <math.h>

static constexpr int B  = 8;
static constexpr int T  = 800;
static constexpr int L  = 192000;
static constexpr int NB = 24;
static constexpr float SCALE = 800.0f / 192000.0f;  // T/L

typedef __bf16 bf8 __attribute__((ext_vector_type(8)));
typedef float  f4  __attribute__((ext_vector_type(4)));

__device__ __forceinline__ float sigf(float x) { return 1.0f / (1.0f + __expf(-x)); }
__device__ __forceinline__ float leaky(float x) { return x >= 0.0f ? x : 0.1f * x; }
__device__ __forceinline__ unsigned short f2bf(float f) {
    unsigned u = __float_as_uint(f);
    u = u + 0x7FFFu + ((u >> 16) & 1u);
    return (unsigned short)(u >> 16);
}
__device__ __forceinline__ float bflo(unsigned u) { return __uint_as_float(u << 16); }
__device__ __forceinline__ float bfhi(unsigned u) { return __uint_as_float(u & 0xffff0000u); }

__device__ __forceinline__ void interp_idx(int l, int& i0, int& i1, float& w) {
    float pos = ((float)l + 0.5f) * SCALE - 0.5f;
    pos = fminf(fmaxf(pos, 0.0f), (float)(T - 1));
    i0 = (int)pos;
    i1 = min(i0 + 1, T - 1);
    w = pos - (float)i0;
}

// ---- weight transpose+cast: conv weights -> [tap][cout][cin] bf16 ----
__global__ __launch_bounds__(256) void k_twm(const float* __restrict__ w1,
                                             const float* __restrict__ w2,
                                             const float* __restrict__ wss,
                                             unsigned short* __restrict__ wT1,
                                             unsigned short* __restrict__ wT2,
                                             unsigned short* __restrict__ wTs) {
    int idx = blockIdx.x * 256 + threadIdx.x;
    if (idx < 98304) {                        // np_w1 [256][128][3]
        int tap = idx / (256 * 128), r = idx % (256 * 128);
        int cout = r / 128, cin = r % 128;
        wT1[idx] = f2bf(w1[(cout * 128 + cin) * 3 + tap]);
    } else if (idx < 98304 + 196608) {        // np_w2 [256][256][3]
        int j = idx - 98304;
        int tap = j / (256 * 256), r = j % (256 * 256);
        int cout = r / 256, cin = r % 256;
        wT2[j] = f2bf(w2[(cout * 256 + cin) * 3 + tap]);
    } else if (idx < 98304 + 196608 + 49152) {// ss_w1 [128][128][3]
        int j = idx - 294912;
        int tap = j / (128 * 128), r = j % (128 * 128);
        int cout = r / 128, cin = r % 128;
        wTs[j] = f2bf(wss[(cout * 128 + cin) * 3 + tap]);
    }
}

// ---- mega (512 thr / 8 waves, 32-col t-tile): z=0 -> np chain; z=1 -> ss chain ----
// 32-col tile: each weight A-frag feeds 2 n-tiles (2x reuse), and per-tap weight
// frags are batch-loaded into register arrays before the MFMA burst.
union SMem {
    struct {
        unsigned short xs[50 * 136];     // cond cols t0-2 .. t0+47 (only ..t0+33 used)
        unsigned short h1s[34 * 264];    // h1 cols t0-1 .. t0+32 (zeroed outside [0,T))
        unsigned short h2s[32 * 264];    // h2 cols t0 .. t0+31
        float bnd[32][25];
    } np;
    struct {
        unsigned short xs[34 * 136];     // cond cols t0-1 .. t0+32
        unsigned short gs[32 * 136];
        float sv[32][5];
        float nws[32][5];
    } ss;
};

__global__ __launch_bounds__(512) void k_mega(const float* __restrict__ cond,
                                              const unsigned short* __restrict__ wT1,
                                              const float* __restrict__ b1,
                                              const unsigned short* __restrict__ wT2,
                                              const float* __restrict__ b2np,
                                              const float* __restrict__ w3,
                                              const float* __restrict__ b3,
                                              const float* __restrict__ fbw,
                                              const unsigned short* __restrict__ wTs,
                                              const float* __restrict__ bss,
                                              const float* __restrict__ w2ss,
                                              const float* __restrict__ b2ss,
                                              const float* __restrict__ ntf,
                                              float* __restrict__ h_all,
                                              float* __restrict__ g_all,
                                              float* __restrict__ attack,
                                              float* __restrict__ inten) {
    __shared__ SMem sm;
    const int b = blockIdx.y;
    const int t0 = blockIdx.x * 32;
    const int tid = threadIdx.x;
    const int wave = tid >> 6, lane = tid & 63;   // 8 waves
    const int nfr = lane & 15;
    const int ko8 = (lane >> 4) * 8;
    const int rb = (lane >> 4) * 4;
    const int tcol = lane & 15;

    if (blockIdx.z == 0) {
        // ================= NP chain =================
        for (int i = tid; i < 50 * 128; i += 512) {
            int cin = i / 50, j = i % 50;
            int t = t0 - 2 + j;
            sm.np.xs[j * 136 + cin] = (t >= 0 && t < T) ? f2bf(cond[(b * 128 + cin) * T + t])
                                                        : (unsigned short)0;
        }
        __syncthreads();
        const int coutb = wave * 32;    // 8 waves x 32 couts = 256
        // conv1: 3 n-tiles (output cols t0-1 .. t0+46; first 34 kept), 2 m/wave
        f4 a1[3][2] = {};
#pragma unroll
        for (int tap = 0; tap < 3; ++tap) {
            bf8 aw[2][4];
#pragma unroll
            for (int m = 0; m < 2; ++m)
#pragma unroll
                for (int q = 0; q < 4; ++q)
                    aw[m][q] = *reinterpret_cast<const bf8*>(
                        wT1 + ((tap * 256 + coutb + m * 16 + nfr) * 128 + q * 32 + ko8));
#pragma unroll
            for (int q = 0; q < 4; ++q) {
                bf8 bv0 = *reinterpret_cast<const bf8*>(&sm.np.xs[(nfr + tap) * 136 + q * 32 + ko8]);
                bf8 bv1 = *reinterpret_cast<const bf8*>(&sm.np.xs[(nfr + 16 + tap) * 136 + q * 32 + ko8]);
                bf8 bv2 = *reinterpret_cast<const bf8*>(&sm.np.xs[(nfr + 32 + tap) * 136 + q * 32 + ko8]);
#pragma unroll
                for (int m = 0; m < 2; ++m) {
                    a1[0][m] = __builtin_amdgcn_mfma_f32_16x16x32_bf16(aw[m][q], bv0, a1[0][m], 0, 0, 0);
                    a1[1][m] = __builtin_amdgcn_mfma_f32_16x16x32_bf16(aw[m][q], bv1, a1[1][m], 0, 0, 0);
                    a1[2][m] = __builtin_amdgcn_mfma_f32_16x16x32_bf16(aw[m][q], bv2, a1[2][m], 0, 0, 0);
                }
            }
        }
        // h1 -> LDS; cols outside [0,T) are EXACT zeros (conv2's zero padding)
#pragma unroll
        for (int nt = 0; nt < 3; ++nt) {
            int lcol = nt * 16 + tcol;
            if (lcol < 34) {
                int gcol = t0 - 1 + lcol;
                bool ok = (gcol >= 0 && gcol < T);
#pragma unroll
                for (int m = 0; m < 2; ++m) {
                    ushort4 pk;
                    if (ok) {
                        pk.x = f2bf(leaky(a1[nt][m][0] + b1[coutb + m * 16 + rb + 0]));
                        pk.y = f2bf(leaky(a1[nt][m][1] + b1[coutb + m * 16 + rb + 1]));
                        pk.z = f2bf(leaky(a1[nt][m][2] + b1[coutb + m * 16 + rb + 2]));
                        pk.w = f2bf(leaky(a1[nt][m][3] + b1[coutb + m * 16 + rb + 3]));
                    } else {
                        pk.x = pk.y = pk.z = pk.w = 0;
                    }
                    *reinterpret_cast<ushort4*>(&sm.np.h1s[lcol * 264 + coutb + m * 16 + rb]) = pk;
                }
            }
        }
        __syncthreads();
        // conv2: 256->256, 2 n-tiles x 2 m-tiles; per-tap batched A-loads
        f4 a2[2][2] = {};   // [nv][m]
#pragma unroll
        for (int tap = 0; tap < 3; ++tap) {
            bf8 aw[2][8];
#pragma unroll
            for (int m = 0; m < 2; ++m)
#pragma unroll
                for (int q = 0; q < 8; ++q)
                    aw[m][q] = *reinterpret_cast<const bf8*>(
                        wT2 + ((tap * 256 + coutb + m * 16 + nfr) * 256 + q * 32 + ko8));
#pragma unroll
            for (int q = 0; q < 8; ++q) {
                bf8 bv0 = *reinterpret_cast<const bf8*>(&sm.np.h1s[(nfr + tap) * 264 + q * 32 + ko8]);
                bf8 bv1 = *reinterpret_cast<const bf8*>(&sm.np.h1s[(nfr + 16 + tap) * 264 + q * 32 + ko8]);
#pragma unroll
                for (int m = 0; m < 2; ++m) {
                    a2[0][m] = __builtin_amdgcn_mfma_f32_16x16x32_bf16(aw[m][q], bv0, a2[0][m], 0, 0, 0);
                    a2[1][m] = __builtin_amdgcn_mfma_f32_16x16x32_bf16(aw[m][q], bv1, a2[1][m], 0, 0, 0);
                }
            }
        }
#pragma unroll
        for (int nv = 0; nv < 2; ++nv)
#pragma unroll
            for (int m = 0; m < 2; ++m) {
                ushort4 pk;
                pk.x = f2bf(leaky(a2[nv][m][0] + b2np[coutb + m * 16 + rb + 0]));
                pk.y = f2bf(leaky(a2[nv][m][1] + b2np[coutb + m * 16 + rb + 1]));
                pk.z = f2bf(leaky(a2[nv][m][2] + b2np[coutb + m * 16 + rb + 2]));
                pk.w = f2bf(leaky(a2[nv][m][3] + b2np[coutb + m * 16 + rb + 3]));
                *reinterpret_cast<ushort4*>(&sm.np.h2s[(nv * 16 + tcol) * 264 + coutb + m * 16 + rb]) = pk;
            }
        __syncthreads();
        // head in f32; item i -> (c = i>>5, t = i&31); 864 items
        for (int i = tid; i < 27 * 32; i += 512) {
            int c = i >> 5, t = i & 31;
            float s = b3[c];
            const unsigned short* hp = &sm.np.h2s[t * 264];
            const float* wp3 = w3 + c * 256;
#pragma unroll 4
            for (int kk = 0; kk < 256; kk += 8) {
                uint4 u = *reinterpret_cast<const uint4*>(hp + kk);
                float4 wa = *reinterpret_cast<const float4*>(wp3 + kk);
                float4 wb = *reinterpret_cast<const float4*>(wp3 + kk + 4);
                s += bflo(u.x) * wa.x + bfhi(u.x) * wa.y
                   + bflo(u.y) * wa.z + bfhi(u.y) * wa.w
                   + bflo(u.z) * wb.x + bfhi(u.z) * wb.y
                   + bflo(u.w) * wb.z + bfhi(u.w) * wb.w;
            }
            if (c < 24) sm.np.bnd[t][c] = sigf(s);
            else if (c == 24) attack[b * T + t0 + t] = sigf(s) * 10.0f;
            else if (c == 26) inten[b * T + t0 + t] = sigf(s);
        }
        __syncthreads();
        // h_all[b][k][t] = sum_c bnd[t][c] * fbw[c][k]; 992 items
        for (int i = tid; i < 31 * 32; i += 512) {
            int k = i >> 5, t = i & 31;
            float s = 0.0f;
#pragma unroll
            for (int c = 0; c < NB; ++c) s += sm.np.bnd[t][c] * fbw[c * 31 + k];
            h_all[(b * 31 + k) * T + t0 + t] = s;
        }
    } else {
        // ================= SS chain =================
        for (int i = tid; i < 34 * 128; i += 512) {
            int cin = i / 34, tr = i % 34;
            int t = t0 + tr - 1;
            sm.ss.xs[tr * 136 + cin] = (t >= 0 && t < T) ? f2bf(cond[(b * 128 + cin) * T + t])
                                                         : (unsigned short)0;
        }
        __syncthreads();
        const int coutb = wave * 16;    // 8 waves x 16 couts = 128
        f4 acc[2] = {};                 // [nv]
#pragma unroll
        for (int tap = 0; tap < 3; ++tap) {
            bf8 aw[4];
#pragma unroll
            for (int q = 0; q < 4; ++q)
                aw[q] = *reinterpret_cast<const bf8*>(
                    wTs + ((tap * 128 + coutb + nfr) * 128 + q * 32 + ko8));
#pragma unroll
            for (int q = 0; q < 4; ++q) {
                bf8 bv0 = *reinterpret_cast<const bf8*>(&sm.ss.xs[(nfr + tap) * 136 + q * 32 + ko8]);
                bf8 bv1 = *reinterpret_cast<const bf8*>(&sm.ss.xs[(nfr + 16 + tap) * 136 + q * 32 + ko8]);
                acc[0] = __builtin_amdgcn_mfma_f32_16x16x32_bf16(aw[q], bv0, acc[0], 0, 0, 0);
                acc[1] = __builtin_amdgcn_mfma_f32_16x16x32_bf16(aw[q], bv1, acc[1], 0, 0, 0);
            }
        }
#pragma unroll
        for (int nv = 0; nv < 2; ++nv) {
            ushort4 pk;
            pk.x = f2bf(leaky(acc[nv][0] + bss[coutb + rb + 0]));
            pk.y = f2bf(leaky(acc[nv][1] + bss[coutb + rb + 1]));
            pk.z = f2bf(leaky(acc[nv][2] + bss[coutb + rb + 2]));
            pk.w = f2bf(leaky(acc[nv][3] + bss[coutb + rb + 3]));
            *reinterpret_cast<ushort4*>(&sm.ss.gs[(nv * 16 + tcol) * 136 + coutb + rb]) = pk;
        }
        __syncthreads();
        if (tid < 128) {
            int c = tid & 3, tl = tid >> 2;   // tl 0..31
            float s = b2ss[c];
#pragma unroll
            for (int kk = 0; kk < 128; kk += 8) {
                uint4 u = *reinterpret_cast<const uint4*>(&sm.ss.gs[tl * 136 + kk]);
                float4 wa = *reinterpret_cast<const float4*>(&w2ss[c * 128 + kk]);
                float4 wb = *reinterpret_cast<const float4*>(&w2ss[c * 128 + kk + 4]);
                s += bflo(u.x) * wa.x + bfhi(u.x) * wa.y
                   + bflo(u.y) * wa.z + bfhi(u.y) * wa.w
                   + bflo(u.z) * wb.x + bfhi(u.z) * wb.y
                   + bflo(u.w) * wb.z + bfhi(u.w) * wb.w;
            }
            sm.ss.sv[tl][c] = s;
        }
        __syncthreads();
        if (tid < 32) {
            float a0 = sm.ss.sv[tid][0], a1v = sm.ss.sv[tid][1];
            float a2v = sm.ss.sv[tid][2], a3v = sm.ss.sv[tid][3];
            float m = fmaxf(fmaxf(a0, a1v), fmaxf(a2v, a3v));
            float e0 = __expf(a0 - m), e1 = __expf(a1v - m);
            float e2 = __expf(a2v - m), e3 = __expf(a3v - m);
            float inv = 1.0f / (e0 + e1 + e2 + e3);
            sm.ss.nws[tid][0] = e0 * inv; sm.ss.nws[tid][1] = e1 * inv;
            sm.ss.nws[tid][2] = e2 * inv; sm.ss.nws[tid][3] = e3 * inv;
        }
        __syncthreads();
        for (int i = tid; i < 63 * 32; i += 512) {
            int k = i >> 5, t = i & 31;
            float s = sm.ss.nws[t][0] * ntf[k] + sm.ss.nws[t][1] * ntf[63 + k]
                    + sm.ss.nws[t][2] * ntf[126 + k] + sm.ss.nws[t][3] * ntf[189 + k];
            g_all[(b * 63 + k) * T + t0 + t] = s;
        }
    }
}

// ---------------- fused sample-rate (unchanged, passing numerics) ----------------
__device__ __forceinline__ float interp_T(const float* __restrict__ a, int b, int p) {
    int i0, i1; float w;
    interp_idx(p, i0, i1, w);
    return a[b * T + i0] * (1.0f - w) + a[b * T + i1] * w;
}

__device__ __forceinline__ int refl(int p) {
    return p < 0 ? -p : (p >= L ? 2 * L - 2 - p : p);
}

__global__ __launch_bounds__(256) void k_sr(const float* __restrict__ wn,
                                            const float* __restrict__ g_all,
                                            const float* __restrict__ h_all,
                                            const float* __restrict__ attack,
                                            const float* __restrict__ inten,
                                            float* __restrict__ out) {
    __shared__ float wns[348];
    __shared__ float gl[4][63];
    __shared__ float hl[4][31];
    __shared__ float flt[286];
    __shared__ float ipl[261];
    __shared__ float gp[260];
    const int b = blockIdx.y;
    const int l0 = blockIdx.x * 256;
    const int tid = threadIdx.x;
    for (int i = tid; i < 348; i += 256) {
        int p = l0 - 46 + i;
        wns[i] = (p >= 0 && p < L) ? wn[b * L + p] : 0.0f;
    }
    int fg0, fgu; float wgu;
    interp_idx(l0 - 15, fg0, fgu, wgu);
    for (int i = tid; i < 376; i += 256) {
        if (i < 252) {
            int j = i / 63, k = i % 63;
            int f = min(fg0 + j, T - 1);
            gl[j][k] = g_all[(b * 63 + k) * T + f];
        } else {
            int j2 = (i - 252) / 31, k2 = (i - 252) % 31;
            int f = min(fg0 + j2, T - 1);
            hl[j2][k2] = h_all[(b * 31 + k2) * T + f];
        }
    }
    for (int i = tid; i < 261; i += 256)
        ipl[i] = interp_T(inten, b, l0 - 3 + i);
    __syncthreads();
    for (int i = tid; i < 260; i += 256) {
        int p = l0 - 2 + i;
        int pr = refl(p);
        float cur = ipl[pr - l0 + 3];
        float prev = (pr == 0) ? cur : ipl[pr - 1 - l0 + 3];
        float diff = cur - prev;
        float ar = interp_T(attack, b, pr);
        float enh = fminf(fmaxf(cur + (diff > 0.1f ? ar * 0.3f : 0.0f), 0.0f), 1.0f);
        gp[i] = (diff > 0.0f) ? enh : cur;
    }
    // flt EXACT zero outside [0,L) (reference zero-pads intermediate `filtered`)
    for (int i = tid; i < 286; i += 256) {
        int p = l0 - 15 + i;
        float v = 0.0f;
        if (p >= 0 && p < L) {
            int i0, i1; float w;
            interp_idx(p, i0, i1, w);
            int d0 = min(max(i0 - fg0, 0), 3);
            int d1 = min(max(i1 - fg0, 0), 3);
            float a0 = 0.0f, a1 = 0.0f;
#pragma unroll
            for (int k = 0; k < 63; ++k) {
                float xk = wns[i + k];
                a0 += xk * gl[d0][k];
                a1 += xk * gl[d1][k];
            }
            v = (1.0f - w) * a0 + w * a1;
        }
        flt[i] = v;
    }
    __syncthreads();
    const int l = l0 + tid;
    int i0, i1; float w;
    interp_idx(l, i0, i1, w);
    int d0 = min(max(i0 - fg0, 0), 3);
    int d1 = min(max(i1 - fg0, 0), 3);
    float a0 = 0.0f, a1 = 0.0f;
#pragma unroll
    for (int k = 0; k < 31; ++k) {
        float xk = flt[tid + k];
        a0 += xk * hl[d0][k];
        a1 += xk * hl[d1][k];
    }
    float shaped = (1.0f - w) * a0 + w * a1;
    float g5 = (gp[tid] + gp[tid + 1] + gp[tid + 2] + gp[tid + 3] + gp[tid + 4]) * 0.2f;
    out[b * L + l] = shaped * g5;
    out[B * L + b * L + l] = g5;
}

extern "C" void kernel_launch(void* const* d_in, const int* in_sizes, int n_in,
                              void* d_out, int out_size, void* d_ws, size_t ws_size,
                              hipStream_t stream) {
    const float* cond  = (const float*)d_in[0];
    const float* wn    = (const float*)d_in[1];
    const float* np_w1 = (const float*)d_in[2];
    const float* np_b1 = (const float*)d_in[3];
    const float* np_w2 = (const float*)d_in[4];
    const float* np_b2 = (const float*)d_in[5];
    const float* np_w3 = (const float*)d_in[6];
    const float* np_b3 = (const float*)d_in[7];
    const float* ss_w1 = (const float*)d_in[8];
    const float* ss_b1 = (const float*)d_in[9];
    const float* ss_w2 = (const float*)d_in[10];
    const float* ss_b2 = (const float*)d_in[11];
    const float* fb_w  = (const float*)d_in[12];
    const float* nt_w  = (const float*)d_in[13];

    char* p = (char*)d_ws;
    unsigned short* wT1 = (unsigned short*)p; p += 196608;   // [3][256][128] bf16
    unsigned short* wT2 = (unsigned short*)p; p += 393216;   // [3][256][256] bf16
    unsigned short* wTs = (unsigned short*)p; p += 98304;    // [3][128][128] bf16
    float* attack = (float*)p; p += 25600;                   // [8][800]
    float* inten  = (float*)p; p += 25600;                   // [8][800]
    float* g_all  = (float*)p; p += 1612800;                 // [8][63][800]
    float* h_all  = (float*)p; p += 793600;                  // [8][31][800]
    float* out = (float*)d_out;

    k_twm<<<1344, 256, 0, stream>>>(np_w1, np_w2, ss_w1, wT1, wT2, wTs);
    k_mega<<<dim3(25, 8, 2), 512, 0, stream>>>(cond, wT1, np_b1, wT2, np_b2, np_w3, np_b3,
                                               fb_w, wTs, ss_b1, ss_w2, ss_b2, nt_w,
                                               h_all, g_all, attack, inten);
    k_sr<<<dim3(750, 8), 256, 0, stream>>>(wn, g_all, h_all, attack, inten, out);
}